// Round 11
// baseline (470.762 us; speedup 1.0000x reference)
//
#include <hip/hip_runtime.h>

#define SEQ 8192
#define DIM 1280
#define NHEADS 16
#define HD 80
#define HDP 96
#define NSEG 8
#define SEG 1024
#define KVB 64
#define NSTEP (SEG / KVB)
#define PST 72

typedef float f32x4 __attribute__((ext_vector_type(4)));
typedef short bf16x8 __attribute__((ext_vector_type(8)));
typedef unsigned int u32;

__device__ __forceinline__ float fast_exp2(float x) {
  return __builtin_amdgcn_exp2f(x);
}

__device__ __forceinline__ short f2bf(float f) {
  unsigned int u = __builtin_bit_cast(unsigned int, f);
  u = (u + 0x7fff + ((u >> 16) & 1)) >> 16;
  return (short)u;
}

// packed f32x2 -> bf16x2 (RNE), D.lo = S0, D.hi = S1. No builtin on gfx950.
__device__ __forceinline__ u32 cvt_pk_bf16(float lo, float hi) {
  u32 r;
  asm("v_cvt_pk_bf16_f32 %0, %1, %2" : "=v"(r) : "v"(lo), "v"(hi));
  return r;
}

typedef __attribute__((address_space(1))) const unsigned int glds_src_t;
typedef __attribute__((address_space(3))) unsigned int glds_dst_t;
__device__ __forceinline__ void gload_lds16(const void* g, void* l) {
  __builtin_amdgcn_global_load_lds((glds_src_t*)g, (glds_dst_t*)l, 16, 0, 0);
}

// ---------------- generic f32 -> bf16 cast (vectorized) ----------------
__global__ void cast_f32_bf16(const float* __restrict__ in, short* __restrict__ out, int n) {
  int n4 = n >> 2;
  for (int i = blockIdx.x * blockDim.x + threadIdx.x; i < n4; i += gridDim.x * blockDim.x) {
    float4 v = ((const float4*)in)[i];
    short4 o;
    o.x = f2bf(v.x); o.y = f2bf(v.y); o.z = f2bf(v.z); o.w = f2bf(v.w);
    ((short4*)out)[i] = o;
  }
}

// ---------------- bf16 GEMM, B^T layout (N,K), f32 out + bias ----------------
// BK=64, XCD-contiguous 1D grid, involution chunk-XOR LDS swizzle.
__global__ __launch_bounds__(256) void gemm_bt_bias(
    const short* __restrict__ A, const short* __restrict__ B,
    const float* __restrict__ bias, float* __restrict__ C,
    int M, int N, int K) {
  __shared__ short As[128 * 64];
  __shared__ short Bs[128 * 64];
  int tid = threadIdx.x;
  int w = tid >> 6, l = tid & 63;
  int lrow = l & 15, lg = l >> 4;
  int bid = blockIdx.x;
  int cpx = gridDim.x >> 3;
  int lid = (bid & 7) * cpx + (bid >> 3);  // XCD-contiguous logical id
  int ntx = N >> 7;
  int m0 = (lid / ntx) * 128, n0 = (lid % ntx) * 128;
  int wm = w & 1, wn = w >> 1;

  f32x4 acc[4][4] = {};

  const char* Abase = (const char*)A + (size_t)m0 * K * 2;
  const char* Bbase = (const char*)B + (size_t)n0 * K * 2;

  for (int k0 = 0; k0 < K; k0 += 64) {
#pragma unroll
    for (int j = 0; j < 4; j++) {
      int c = j * 256 + tid;
      int row = c >> 3;
      int sc = c & 7;
      int slc = sc ^ (row & 7);  // stage-side involution swizzle
      size_t goff = (size_t)row * K * 2 + (size_t)k0 * 2 + slc * 16;
      int loff = (j * 256 + w * 64) * 16;  // wave-uniform LDS base
      gload_lds16(Abase + goff, (char*)As + loff);
      gload_lds16(Bbase + goff, (char*)Bs + loff);
    }
    __syncthreads();
#pragma unroll
    for (int kk = 0; kk < 2; kk++) {
      bf16x8 a[4], b[4];
#pragma unroll
      for (int mt = 0; mt < 4; mt++) {
        int row = wm * 64 + mt * 16 + lrow;
        int p = (kk * 4 + lg) ^ (row & 7);
        a[mt] = *(const bf16x8*)&As[row * 64 + p * 8];
      }
#pragma unroll
      for (int nt = 0; nt < 4; nt++) {
        int row = wn * 64 + nt * 16 + lrow;
        int p = (kk * 4 + lg) ^ (row & 7);
        b[nt] = *(const bf16x8*)&Bs[row * 64 + p * 8];
      }
#pragma unroll
      for (int mt = 0; mt < 4; mt++)
#pragma unroll
        for (int nt = 0; nt < 4; nt++)
          acc[mt][nt] = __builtin_amdgcn_mfma_f32_16x16x32_bf16(a[mt], b[nt], acc[mt][nt], 0, 0, 0);
    }
    __syncthreads();
  }
#pragma unroll
  for (int nt = 0; nt < 4; nt++) {
    int col = n0 + wn * 64 + nt * 16 + lrow;
    float bv = bias[col];
#pragma unroll
    for (int mt = 0; mt < 4; mt++) {
      int mrow = m0 + wm * 64 + mt * 16 + lg * 4;
#pragma unroll
      for (int r = 0; r < 4; r++)
        C[(size_t)(mrow + r) * N + col] = acc[mt][nt][r] + bv;
    }
  }
}

// ---------------- RoPE for q,k (f32 in, bf16 out, head-major, pad to 96) ----------------
// q additionally scaled by 80^-0.5 * log2(e) (softmax done in exp2 domain).
__global__ void rope_qk(const float* __restrict__ qkv, const float* __restrict__ cosb,
                        const float* __restrict__ sinb, short* __restrict__ qg,
                        short* __restrict__ kg) {
  int t = blockIdx.x * blockDim.x + threadIdx.x;
  if (t >= SEQ * NHEADS * 40) return;
  int d = t % 40;
  int h = (t / 40) & 15;
  int s = t / 640;
  const float* row = qkv + (size_t)s * (3 * DIM);
  float c0 = cosb[s * HD + d], c1 = cosb[s * HD + d + 40];
  float s0 = sinb[s * HD + d], s1 = sinb[s * HD + d + 40];
  float x1 = row[h * HD + d], x2 = row[h * HD + d + 40];
  float q0 = x1 * c0 - x2 * s0;
  float q1 = x2 * c1 + x1 * s1;
  float y1 = row[DIM + h * HD + d], y2 = row[DIM + h * HD + d + 40];
  float k0 = y1 * c0 - y2 * s0;
  float k1 = y2 * c1 + y1 * s1;
  const float sc = 0.11180339887498949f * 1.4426950408889634f;
  size_t base = ((size_t)h * SEQ + s) * HDP;
  qg[base + d] = f2bf(q0 * sc);
  qg[base + d + 40] = f2bf(q1 * sc);
  kg[base + d] = f2bf(k0);
  kg[base + d + 40] = f2bf(k1);
  if (d < 16) { qg[base + 80 + d] = 0; kg[base + 80 + d] = 0; }
}

// ---------------- V transpose: qkv f32 (S,3,H,80) -> vt bf16 (H,80,S) ----------------
__global__ void v_transpose(const float* __restrict__ qkv, short* __restrict__ vt) {
  __shared__ float T[16][68];
  int st = blockIdx.x, dt = blockIdx.y, h = blockIdx.z;
  int d0 = dt * 16, s0 = st * 64;
  int t = threadIdx.x;
  int dd = t & 15, ss = t >> 4;
#pragma unroll
  for (int j = 0; j < 4; j++) {
    int s = ss + j * 16;
    T[dd][s] = qkv[(size_t)(s0 + s) * (3 * DIM) + 2 * DIM + h * HD + d0 + dd];
  }
  __syncthreads();
  int s2 = t & 63, dr = t >> 6;
#pragma unroll
  for (int j = 0; j < 4; j++) {
    int d = dr + j * 4;
    vt[((size_t)(h * HD + d0 + d)) * SEQ + s0 + s2] = f2bf(T[d][s2]);
  }
}

// ---------------- flash attention v5 ----------------
// = v4 (K-LDS coop staging) + three micro-opts:
//  (1) v_cvt_pk_bf16_f32 P-pack (halves softmax pack VALU),
//  (2) V loads hoisted to step top, pinned with sched_barrier(0) so HBM/L2
//      latency hides under QK+softmax (compiler sank them in v4),
//  (3) s_setprio(1) around both MFMA clusters (T5).
__global__ __launch_bounds__(512, 4) void attn_kernel(
    const short* __restrict__ qg, const short* __restrict__ kg,
    const short* __restrict__ vt, short* __restrict__ out) {
  __shared__ short Ks[2][64 * 128];  // 32 KB (rows padded 96->128 shorts)
  __shared__ short Pl[8][32 * PST];  // 36 KB
  int bid = blockIdx.x;
  int b = bid & 7, h = (bid >> 3) & 15, qt = bid >> 7;
  int tid = threadIdx.x;
  int w = tid >> 6, l = tid & 63;
  int lrow = l & 15, lg = l >> 4;
  int qbase_s = b * SEG + qt * 256 + w * 32;

  const short* qh = qg + (size_t)h * SEQ * HDP;
  const short* kh = kg + (size_t)h * SEQ * HDP;
  const short* vh = vt + (size_t)h * HD * SEQ;

#define STAGE_K(BUF, KEY0N)                                                    \
  {                                                                            \
    _Pragma("unroll") for (int sr = 0; sr < 2; sr++) {                         \
      int sbase = sr * 512 + w * 64;                                           \
      int ss = sbase + l;                                                      \
      int skey = ss >> 4, sc = ss & 15;                                        \
      int slc = sc ^ (skey & 7);                                               \
      const short* ssrc =                                                      \
          kh + (size_t)((KEY0N) + skey) * HDP + (slc < 12 ? slc * 8 : 0);      \
      gload_lds16(ssrc, (char*)&Ks[BUF][0] + sbase * 16);                      \
    }                                                                          \
  }

  bf16x8 qf[2][3];
#pragma unroll
  for (int mt = 0; mt < 2; mt++)
#pragma unroll
    for (int ks = 0; ks < 3; ks++)
      qf[mt][ks] = *(const bf16x8*)&qh[(size_t)(qbase_s + mt * 16 + lrow) * HDP + ks * 32 + lg * 8];

  f32x4 o[2][5] = {};
  float m_st[2] = {-1e30f, -1e30f};
  float l_st[2] = {0.f, 0.f};

  short* Pw = &Pl[w][0];

  STAGE_K(0, b * SEG);
  __syncthreads();

  for (int i = 0; i < NSTEP; i++) {
    int cur = i & 1;
    int key0 = b * SEG + i * KVB;
    if (i + 1 < NSTEP) {
      STAGE_K(cur ^ 1, key0 + KVB);
    }

    // --- V loads issued EARLY (hide latency under QK + softmax) ---
    bf16x8 vf[5][2];
#pragma unroll
    for (int nt = 0; nt < 5; nt++)
#pragma unroll
      for (int ks = 0; ks < 2; ks++)
        vf[nt][ks] = *(const bf16x8*)&vh[(size_t)(nt * 16 + lrow) * SEQ + key0 + ks * 32 + lg * 8];
    __builtin_amdgcn_sched_barrier(0);  // pin: V loads must issue before QK

    // --- QK^T (swapped: mfma(K,Q), col=query, key in-lane) from LDS ---
    f32x4 sv[2][4] = {};
    __builtin_amdgcn_s_setprio(1);
#pragma unroll
    for (int kt = 0; kt < 4; kt++) {
      bf16x8 kf[3];
      int key = kt * 16 + lrow;
#pragma unroll
      for (int ks = 0; ks < 3; ks++) {
        int p = (ks * 4 + lg) ^ (key & 7);
        kf[ks] = *(const bf16x8*)&Ks[cur][key * 128 + p * 8];
      }
#pragma unroll
      for (int mt = 0; mt < 2; mt++)
#pragma unroll
        for (int ks = 0; ks < 3; ks++)
          sv[mt][kt] = __builtin_amdgcn_mfma_f32_16x16x32_bf16(kf[ks], qf[mt][ks], sv[mt][kt], 0, 0, 0);
    }
    __builtin_amdgcn_s_setprio(0);

    // --- per-query tile max: in-lane over 16 keys, then 2 shfl ---
    float cm[2];
#pragma unroll
    for (int mt = 0; mt < 2; mt++) {
      float a0 = fmaxf(fmaxf(sv[mt][0][0], sv[mt][0][1]), fmaxf(sv[mt][0][2], sv[mt][0][3]));
      float a1 = fmaxf(fmaxf(sv[mt][1][0], sv[mt][1][1]), fmaxf(sv[mt][1][2], sv[mt][1][3]));
      float a2 = fmaxf(fmaxf(sv[mt][2][0], sv[mt][2][1]), fmaxf(sv[mt][2][2], sv[mt][2][3]));
      float a3 = fmaxf(fmaxf(sv[mt][3][0], sv[mt][3][1]), fmaxf(sv[mt][3][2], sv[mt][3][3]));
      float c = fmaxf(fmaxf(a0, a1), fmaxf(a2, a3));
      c = fmaxf(c, __shfl_xor(c, 16));
      c = fmaxf(c, __shfl_xor(c, 32));
      cm[mt] = c;
    }
    // defer-max: rescale only when max grew by > 8 (log2 units)
    if (__any((cm[0] > m_st[0] + 8.f) || (cm[1] > m_st[1] + 8.f))) {
#pragma unroll
      for (int mt = 0; mt < 2; mt++) {
        float mn = fmaxf(m_st[mt], cm[mt]);
        float c = fast_exp2(m_st[mt] - mn);
        m_st[mt] = mn;
        l_st[mt] *= c;
        float cr[4];
#pragma unroll
        for (int r = 0; r < 4; r++) cr[r] = __shfl(c, lg * 4 + r);
#pragma unroll
        for (int nt = 0; nt < 5; nt++)
#pragma unroll
          for (int r = 0; r < 4; r++) o[mt][nt][r] *= cr[r];
      }
    }
    // p = exp2(s - m); accumulate l; packed cvt, one b64 LDS write per 4 keys
#pragma unroll
    for (int mt = 0; mt < 2; mt++) {
      float rs = 0.f;
#pragma unroll
      for (int kt = 0; kt < 4; kt++) {
#pragma unroll
        for (int r = 0; r < 4; r++) {
          sv[mt][kt][r] = fast_exp2(sv[mt][kt][r] - m_st[mt]);
          rs += sv[mt][kt][r];
        }
        uint2 pk;
        pk.x = cvt_pk_bf16(sv[mt][kt][0], sv[mt][kt][1]);
        pk.y = cvt_pk_bf16(sv[mt][kt][2], sv[mt][kt][3]);
        *(uint2*)&Pw[(mt * 16 + lrow) * PST + kt * 16 + lg * 4] = pk;
      }
      rs += __shfl_xor(rs, 16);
      rs += __shfl_xor(rs, 32);
      l_st[mt] += rs;
    }

    // --- PV ---
    bf16x8 pa[2][2];
#pragma unroll
    for (int mt = 0; mt < 2; mt++)
#pragma unroll
      for (int ks = 0; ks < 2; ks++)
        pa[mt][ks] = *(const bf16x8*)&Pw[(mt * 16 + lrow) * PST + ks * 32 + lg * 8];
    __builtin_amdgcn_s_setprio(1);
#pragma unroll
    for (int nt = 0; nt < 5; nt++)
#pragma unroll
      for (int mt = 0; mt < 2; mt++)
#pragma unroll
        for (int ks = 0; ks < 2; ks++)
          o[mt][nt] = __builtin_amdgcn_mfma_f32_16x16x32_bf16(pa[mt][ks], vf[nt][ks], o[mt][nt], 0, 0, 0);
    __builtin_amdgcn_s_setprio(0);

    __syncthreads();  // drain K stage; all QK reads of Ks[cur] done
  }

#pragma unroll
  for (int mt = 0; mt < 2; mt++) {
    float rl = 1.f / l_st[mt];
    float ir[4];
#pragma unroll
    for (int r = 0; r < 4; r++) ir[r] = __shfl(rl, lg * 4 + r);
#pragma unroll
    for (int r = 0; r < 4; r++) {
      int srow = qbase_s + mt * 16 + lg * 4 + r;
#pragma unroll
      for (int nt = 0; nt < 5; nt++)
        out[(size_t)srow * DIM + h * HD + nt * 16 + lrow] = f2bf(o[mt][nt][r] * ir[r]);
    }
  }
}

extern "C" void kernel_launch(void* const* d_in, const int* in_sizes, int n_in,
                              void* d_out, int out_size, void* d_ws, size_t ws_size,
                              hipStream_t stream) {
  const float* hidden = (const float*)d_in[0];
  const float* cosb = (const float*)d_in[1];
  const float* sinb = (const float*)d_in[2];
  const float* qkv_w = (const float*)d_in[3];
  const float* qkv_b = (const float*)d_in[4];
  const float* proj_w = (const float*)d_in[5];
  const float* proj_b = (const float*)d_in[6];

  char* ws = (char*)d_ws;
  float* qkv_f = (float*)(ws);
  short* attn_o = (short*)(ws);
  short* wp_bf = (short*)(ws + 23068672);
  short* q_bf = (short*)(ws + 125829120);
  short* k_bf = (short*)(ws + 150994944);
  short* v_tb = (short*)(ws + 176160768);
  short* h_bf = (short*)(ws + 197132288);
  short* wq_bf = (short*)(ws + 218103808);

  cast_f32_bf16<<<4096, 256, 0, stream>>>(hidden, h_bf, SEQ * DIM);
  cast_f32_bf16<<<4096, 256, 0, stream>>>(qkv_w, wq_bf, 3 * DIM * DIM);
  gemm_bt_bias<<<1920, 256, 0, stream>>>(h_bf, wq_bf, qkv_b, qkv_f, SEQ, 3 * DIM, DIM);
  rope_qk<<<20480, 256, 0, stream>>>(qkv_f, cosb, sinb, q_bf, k_bf);
  v_transpose<<<dim3(128, 5, 16), 256, 0, stream>>>(qkv_f, v_tb);
  cast_f32_bf16<<<2048, 256, 0, stream>>>(proj_w, wp_bf, DIM * DIM);
  attn_kernel<<<512, 512, 0, stream>>>(q_bf, k_bf, v_tb, attn_o);
  gemm_bt_bias<<<640, 256, 0, stream>>>(attn_o, wp_bf, proj_b, (float*)d_out, SEQ, DIM, DIM);
}

// Round 12
// 455.095 us; speedup vs baseline: 1.0344x; 1.0344x over previous
//
#include <hip/hip_runtime.h>

#define SEQ 8192
#define DIM 1280
#define NHEADS 16
#define HD 80
#define HDP 96
#define NSEG 8
#define SEG 1024
#define KVB 64
#define NSTEP (SEG / KVB)
#define PST 72

typedef float f32x4 __attribute__((ext_vector_type(4)));
typedef short bf16x8 __attribute__((ext_vector_type(8)));
typedef unsigned int u32;

__device__ __forceinline__ float fast_exp2(float x) {
  return __builtin_amdgcn_exp2f(x);
}

__device__ __forceinline__ short f2bf(float f) {
  unsigned int u = __builtin_bit_cast(unsigned int, f);
  u = (u + 0x7fff + ((u >> 16) & 1)) >> 16;
  return (short)u;
}

// packed f32x2 -> bf16x2 (RNE), D.lo = S0, D.hi = S1. No builtin on gfx950.
__device__ __forceinline__ u32 cvt_pk_bf16(float lo, float hi) {
  u32 r;
  asm("v_cvt_pk_bf16_f32 %0, %1, %2" : "=v"(r) : "v"(lo), "v"(hi));
  return r;
}

typedef __attribute__((address_space(1))) const unsigned int glds_src_t;
typedef __attribute__((address_space(3))) unsigned int glds_dst_t;
__device__ __forceinline__ void gload_lds16(const void* g, void* l) {
  __builtin_amdgcn_global_load_lds((glds_src_t*)g, (glds_dst_t*)l, 16, 0, 0);
}

// ---------------- generic f32 -> bf16 cast (vectorized) ----------------
__global__ void cast_f32_bf16(const float* __restrict__ in, short* __restrict__ out, int n) {
  int n4 = n >> 2;
  for (int i = blockIdx.x * blockDim.x + threadIdx.x; i < n4; i += gridDim.x * blockDim.x) {
    float4 v = ((const float4*)in)[i];
    short4 o;
    o.x = f2bf(v.x); o.y = f2bf(v.y); o.z = f2bf(v.z); o.w = f2bf(v.w);
    ((short4*)out)[i] = o;
  }
}

// ---------------- bf16 GEMM, B^T layout (N,K), f32 out + bias ----------------
// BK=64, XCD-contiguous 1D grid, involution chunk-XOR LDS swizzle.
__global__ __launch_bounds__(256) void gemm_bt_bias(
    const short* __restrict__ A, const short* __restrict__ B,
    const float* __restrict__ bias, float* __restrict__ C,
    int M, int N, int K) {
  __shared__ short As[128 * 64];
  __shared__ short Bs[128 * 64];
  int tid = threadIdx.x;
  int w = tid >> 6, l = tid & 63;
  int lrow = l & 15, lg = l >> 4;
  int bid = blockIdx.x;
  int cpx = gridDim.x >> 3;
  int lid = (bid & 7) * cpx + (bid >> 3);  // XCD-contiguous logical id
  int ntx = N >> 7;
  int m0 = (lid / ntx) * 128, n0 = (lid % ntx) * 128;
  int wm = w & 1, wn = w >> 1;

  f32x4 acc[4][4] = {};

  const char* Abase = (const char*)A + (size_t)m0 * K * 2;
  const char* Bbase = (const char*)B + (size_t)n0 * K * 2;

  for (int k0 = 0; k0 < K; k0 += 64) {
#pragma unroll
    for (int j = 0; j < 4; j++) {
      int c = j * 256 + tid;
      int row = c >> 3;
      int sc = c & 7;
      int slc = sc ^ (row & 7);  // stage-side involution swizzle
      size_t goff = (size_t)row * K * 2 + (size_t)k0 * 2 + slc * 16;
      int loff = (j * 256 + w * 64) * 16;  // wave-uniform LDS base
      gload_lds16(Abase + goff, (char*)As + loff);
      gload_lds16(Bbase + goff, (char*)Bs + loff);
    }
    __syncthreads();
#pragma unroll
    for (int kk = 0; kk < 2; kk++) {
      bf16x8 a[4], b[4];
#pragma unroll
      for (int mt = 0; mt < 4; mt++) {
        int row = wm * 64 + mt * 16 + lrow;
        int p = (kk * 4 + lg) ^ (row & 7);
        a[mt] = *(const bf16x8*)&As[row * 64 + p * 8];
      }
#pragma unroll
      for (int nt = 0; nt < 4; nt++) {
        int row = wn * 64 + nt * 16 + lrow;
        int p = (kk * 4 + lg) ^ (row & 7);
        b[nt] = *(const bf16x8*)&Bs[row * 64 + p * 8];
      }
#pragma unroll
      for (int mt = 0; mt < 4; mt++)
#pragma unroll
        for (int nt = 0; nt < 4; nt++)
          acc[mt][nt] = __builtin_amdgcn_mfma_f32_16x16x32_bf16(a[mt], b[nt], acc[mt][nt], 0, 0, 0);
    }
    __syncthreads();
  }
#pragma unroll
  for (int nt = 0; nt < 4; nt++) {
    int col = n0 + wn * 64 + nt * 16 + lrow;
    float bv = bias[col];
#pragma unroll
    for (int mt = 0; mt < 4; mt++) {
      int mrow = m0 + wm * 64 + mt * 16 + lg * 4;
#pragma unroll
      for (int r = 0; r < 4; r++)
        C[(size_t)(mrow + r) * N + col] = acc[mt][nt][r] + bv;
    }
  }
}

// ---------------- RoPE for q,k (f32 in, bf16 out, head-major, pad to 96) ----------------
// q additionally scaled by 80^-0.5 * log2(e) (softmax done in exp2 domain).
__global__ void rope_qk(const float* __restrict__ qkv, const float* __restrict__ cosb,
                        const float* __restrict__ sinb, short* __restrict__ qg,
                        short* __restrict__ kg) {
  int t = blockIdx.x * blockDim.x + threadIdx.x;
  if (t >= SEQ * NHEADS * 40) return;
  int d = t % 40;
  int h = (t / 40) & 15;
  int s = t / 640;
  const float* row = qkv + (size_t)s * (3 * DIM);
  float c0 = cosb[s * HD + d], c1 = cosb[s * HD + d + 40];
  float s0 = sinb[s * HD + d], s1 = sinb[s * HD + d + 40];
  float x1 = row[h * HD + d], x2 = row[h * HD + d + 40];
  float q0 = x1 * c0 - x2 * s0;
  float q1 = x2 * c1 + x1 * s1;
  float y1 = row[DIM + h * HD + d], y2 = row[DIM + h * HD + d + 40];
  float k0 = y1 * c0 - y2 * s0;
  float k1 = y2 * c1 + y1 * s1;
  const float sc = 0.11180339887498949f * 1.4426950408889634f;
  size_t base = ((size_t)h * SEQ + s) * HDP;
  qg[base + d] = f2bf(q0 * sc);
  qg[base + d + 40] = f2bf(q1 * sc);
  kg[base + d] = f2bf(k0);
  kg[base + d + 40] = f2bf(k1);
  if (d < 16) { qg[base + 80 + d] = 0; kg[base + 80 + d] = 0; }
}

// ---------------- V transpose: qkv f32 (S,3,H,80) -> vt bf16 (H,80,S) ----------------
__global__ void v_transpose(const float* __restrict__ qkv, short* __restrict__ vt) {
  __shared__ float T[16][68];
  int st = blockIdx.x, dt = blockIdx.y, h = blockIdx.z;
  int d0 = dt * 16, s0 = st * 64;
  int t = threadIdx.x;
  int dd = t & 15, ss = t >> 4;
#pragma unroll
  for (int j = 0; j < 4; j++) {
    int s = ss + j * 16;
    T[dd][s] = qkv[(size_t)(s0 + s) * (3 * DIM) + 2 * DIM + h * HD + d0 + dd];
  }
  __syncthreads();
  int s2 = t & 63, dr = t >> 6;
#pragma unroll
  for (int j = 0; j < 4; j++) {
    int d = dr + j * 4;
    vt[((size_t)(h * HD + d0 + d)) * SEQ + s0 + s2] = f2bf(T[d][s2]);
  }
}

// ---------------- flash attention v6 ----------------
// = v4 (K-LDS coop staging, 135us) + cvt_pk P-pack + setprio, with the V
// global loads batched right after the QK cluster (NO sched_barrier — the
// r11 full fence forced a scratch spill at VGPR=64). If the compiler keeps
// the batch, V latency hides under softmax; if it sinks it, we match v4.
__global__ __launch_bounds__(512, 4) void attn_kernel(
    const short* __restrict__ qg, const short* __restrict__ kg,
    const short* __restrict__ vt, short* __restrict__ out) {
  __shared__ short Ks[2][64 * 128];  // 32 KB (rows padded 96->128 shorts)
  __shared__ short Pl[8][32 * PST];  // 36 KB
  int bid = blockIdx.x;
  int b = bid & 7, h = (bid >> 3) & 15, qt = bid >> 7;
  int tid = threadIdx.x;
  int w = tid >> 6, l = tid & 63;
  int lrow = l & 15, lg = l >> 4;
  int qbase_s = b * SEG + qt * 256 + w * 32;

  const short* qh = qg + (size_t)h * SEQ * HDP;
  const short* kh = kg + (size_t)h * SEQ * HDP;
  const short* vh = vt + (size_t)h * HD * SEQ;

#define STAGE_K(BUF, KEY0N)                                                    \
  {                                                                            \
    _Pragma("unroll") for (int sr = 0; sr < 2; sr++) {                         \
      int sbase = sr * 512 + w * 64;                                           \
      int ss = sbase + l;                                                      \
      int skey = ss >> 4, sc = ss & 15;                                        \
      int slc = sc ^ (skey & 7);                                               \
      const short* ssrc =                                                      \
          kh + (size_t)((KEY0N) + skey) * HDP + (slc < 12 ? slc * 8 : 0);      \
      gload_lds16(ssrc, (char*)&Ks[BUF][0] + sbase * 16);                      \
    }                                                                          \
  }

  bf16x8 qf[2][3];
#pragma unroll
  for (int mt = 0; mt < 2; mt++)
#pragma unroll
    for (int ks = 0; ks < 3; ks++)
      qf[mt][ks] = *(const bf16x8*)&qh[(size_t)(qbase_s + mt * 16 + lrow) * HDP + ks * 32 + lg * 8];

  f32x4 o[2][5] = {};
  float m_st[2] = {-1e30f, -1e30f};
  float l_st[2] = {0.f, 0.f};

  short* Pw = &Pl[w][0];

  STAGE_K(0, b * SEG);
  __syncthreads();

  for (int i = 0; i < NSTEP; i++) {
    int cur = i & 1;
    int key0 = b * SEG + i * KVB;
    if (i + 1 < NSTEP) {
      STAGE_K(cur ^ 1, key0 + KVB);
    }

    // --- QK^T (swapped: mfma(K,Q), col=query, key in-lane) from LDS ---
    f32x4 sv[2][4] = {};
    __builtin_amdgcn_s_setprio(1);
#pragma unroll
    for (int kt = 0; kt < 4; kt++) {
      bf16x8 kf[3];
      int key = kt * 16 + lrow;
#pragma unroll
      for (int ks = 0; ks < 3; ks++) {
        int p = (ks * 4 + lg) ^ (key & 7);
        kf[ks] = *(const bf16x8*)&Ks[cur][key * 128 + p * 8];
      }
#pragma unroll
      for (int mt = 0; mt < 2; mt++)
#pragma unroll
        for (int ks = 0; ks < 3; ks++)
          sv[mt][kt] = __builtin_amdgcn_mfma_f32_16x16x32_bf16(kf[ks], qf[mt][ks], sv[mt][kt], 0, 0, 0);
    }
    __builtin_amdgcn_s_setprio(0);

    // --- V loads, batched here (no fence): latency overlaps softmax below ---
    bf16x8 vf[5][2];
#pragma unroll
    for (int nt = 0; nt < 5; nt++)
#pragma unroll
      for (int ks = 0; ks < 2; ks++)
        vf[nt][ks] = *(const bf16x8*)&vh[(size_t)(nt * 16 + lrow) * SEQ + key0 + ks * 32 + lg * 8];

    // --- per-query tile max: in-lane over 16 keys, then 2 shfl ---
    float cm[2];
#pragma unroll
    for (int mt = 0; mt < 2; mt++) {
      float a0 = fmaxf(fmaxf(sv[mt][0][0], sv[mt][0][1]), fmaxf(sv[mt][0][2], sv[mt][0][3]));
      float a1 = fmaxf(fmaxf(sv[mt][1][0], sv[mt][1][1]), fmaxf(sv[mt][1][2], sv[mt][1][3]));
      float a2 = fmaxf(fmaxf(sv[mt][2][0], sv[mt][2][1]), fmaxf(sv[mt][2][2], sv[mt][2][3]));
      float a3 = fmaxf(fmaxf(sv[mt][3][0], sv[mt][3][1]), fmaxf(sv[mt][3][2], sv[mt][3][3]));
      float c = fmaxf(fmaxf(a0, a1), fmaxf(a2, a3));
      c = fmaxf(c, __shfl_xor(c, 16));
      c = fmaxf(c, __shfl_xor(c, 32));
      cm[mt] = c;
    }
    // defer-max: rescale only when max grew by > 8 (log2 units)
    if (__any((cm[0] > m_st[0] + 8.f) || (cm[1] > m_st[1] + 8.f))) {
#pragma unroll
      for (int mt = 0; mt < 2; mt++) {
        float mn = fmaxf(m_st[mt], cm[mt]);
        float c = fast_exp2(m_st[mt] - mn);
        m_st[mt] = mn;
        l_st[mt] *= c;
        float cr[4];
#pragma unroll
        for (int r = 0; r < 4; r++) cr[r] = __shfl(c, lg * 4 + r);
#pragma unroll
        for (int nt = 0; nt < 5; nt++)
#pragma unroll
          for (int r = 0; r < 4; r++) o[mt][nt][r] *= cr[r];
      }
    }
    // p = exp2(s - m); accumulate l; packed cvt, one b64 LDS write per 4 keys
#pragma unroll
    for (int mt = 0; mt < 2; mt++) {
      float rs = 0.f;
#pragma unroll
      for (int kt = 0; kt < 4; kt++) {
#pragma unroll
        for (int r = 0; r < 4; r++) {
          sv[mt][kt][r] = fast_exp2(sv[mt][kt][r] - m_st[mt]);
          rs += sv[mt][kt][r];
        }
        uint2 pk;
        pk.x = cvt_pk_bf16(sv[mt][kt][0], sv[mt][kt][1]);
        pk.y = cvt_pk_bf16(sv[mt][kt][2], sv[mt][kt][3]);
        *(uint2*)&Pw[(mt * 16 + lrow) * PST + kt * 16 + lg * 4] = pk;
      }
      rs += __shfl_xor(rs, 16);
      rs += __shfl_xor(rs, 32);
      l_st[mt] += rs;
    }

    // --- PV ---
    bf16x8 pa[2][2];
#pragma unroll
    for (int mt = 0; mt < 2; mt++)
#pragma unroll
      for (int ks = 0; ks < 2; ks++)
        pa[mt][ks] = *(const bf16x8*)&Pw[(mt * 16 + lrow) * PST + ks * 32 + lg * 8];
    __builtin_amdgcn_s_setprio(1);
#pragma unroll
    for (int nt = 0; nt < 5; nt++)
#pragma unroll
      for (int mt = 0; mt < 2; mt++)
#pragma unroll
        for (int ks = 0; ks < 2; ks++)
          o[mt][nt] = __builtin_amdgcn_mfma_f32_16x16x32_bf16(pa[mt][ks], vf[nt][ks], o[mt][nt], 0, 0, 0);
    __builtin_amdgcn_s_setprio(0);

    __syncthreads();  // drain K stage; all QK reads of Ks[cur] done
  }

#pragma unroll
  for (int mt = 0; mt < 2; mt++) {
    float rl = 1.f / l_st[mt];
    float ir[4];
#pragma unroll
    for (int r = 0; r < 4; r++) ir[r] = __shfl(rl, lg * 4 + r);
#pragma unroll
    for (int r = 0; r < 4; r++) {
      int srow = qbase_s + mt * 16 + lg * 4 + r;
#pragma unroll
      for (int nt = 0; nt < 5; nt++)
        out[(size_t)srow * DIM + h * HD + nt * 16 + lrow] = f2bf(o[mt][nt][r] * ir[r]);
    }
  }
}

extern "C" void kernel_launch(void* const* d_in, const int* in_sizes, int n_in,
                              void* d_out, int out_size, void* d_ws, size_t ws_size,
                              hipStream_t stream) {
  const float* hidden = (const float*)d_in[0];
  const float* cosb = (const float*)d_in[1];
  const float* sinb = (const float*)d_in[2];
  const float* qkv_w = (const float*)d_in[3];
  const float* qkv_b = (const float*)d_in[4];
  const float* proj_w = (const float*)d_in[5];
  const float* proj_b = (const float*)d_in[6];

  char* ws = (char*)d_ws;
  float* qkv_f = (float*)(ws);
  short* attn_o = (short*)(ws);
  short* wp_bf = (short*)(ws + 23068672);
  short* q_bf = (short*)(ws + 125829120);
  short* k_bf = (short*)(ws + 150994944);
  short* v_tb = (short*)(ws + 176160768);
  short* h_bf = (short*)(ws + 197132288);
  short* wq_bf = (short*)(ws + 218103808);

  cast_f32_bf16<<<4096, 256, 0, stream>>>(hidden, h_bf, SEQ * DIM);
  cast_f32_bf16<<<4096, 256, 0, stream>>>(qkv_w, wq_bf, 3 * DIM * DIM);
  gemm_bt_bias<<<1920, 256, 0, stream>>>(h_bf, wq_bf, qkv_b, qkv_f, SEQ, 3 * DIM, DIM);
  rope_qk<<<20480, 256, 0, stream>>>(qkv_f, cosb, sinb, q_bf, k_bf);
  v_transpose<<<dim3(128, 5, 16), 256, 0, stream>>>(qkv_f, v_tb);
  cast_f32_bf16<<<2048, 256, 0, stream>>>(proj_w, wp_bf, DIM * DIM);
  attn_kernel<<<512, 512, 0, stream>>>(q_bf, k_bf, v_tb, attn_o);
  gemm_bt_bias<<<640, 256, 0, stream>>>(attn_o, wp_bf, proj_b, (float*)d_out, SEQ, DIM, DIM);
}

// Round 13
// 348.676 us; speedup vs baseline: 1.3501x; 1.3052x over previous
//
#include <hip/hip_runtime.h>

#define SEQ 8192
#define DIM 1280
#define NHEADS 16
#define HD 80
#define HDP 96
#define NSEG 8
#define SEG 1024
#define KVB 64
#define NSTEP (SEG / KVB)
#define PST 72

typedef float f32x4 __attribute__((ext_vector_type(4)));
typedef short bf16x8 __attribute__((ext_vector_type(8)));
typedef unsigned int u32;

__device__ __forceinline__ float fast_exp2(float x) {
  return __builtin_amdgcn_exp2f(x);
}

__device__ __forceinline__ short f2bf(float f) {
  unsigned int u = __builtin_bit_cast(unsigned int, f);
  u = (u + 0x7fff + ((u >> 16) & 1)) >> 16;
  return (short)u;
}

// packed f32x2 -> bf16x2 (RNE), D.lo = S0, D.hi = S1. No builtin on gfx950.
__device__ __forceinline__ u32 cvt_pk_bf16(float lo, float hi) {
  u32 r;
  asm("v_cvt_pk_bf16_f32 %0, %1, %2" : "=v"(r) : "v"(lo), "v"(hi));
  return r;
}

typedef __attribute__((address_space(1))) const unsigned int glds_src_t;
typedef __attribute__((address_space(3))) unsigned int glds_dst_t;
__device__ __forceinline__ void gload_lds16(const void* g, void* l) {
  __builtin_amdgcn_global_load_lds((glds_src_t*)g, (glds_dst_t*)l, 16, 0, 0);
}

// ---------------- generic f32 -> bf16 cast (vectorized) ----------------
__global__ void cast_f32_bf16(const float* __restrict__ in, short* __restrict__ out, int n) {
  int n4 = n >> 2;
  for (int i = blockIdx.x * blockDim.x + threadIdx.x; i < n4; i += gridDim.x * blockDim.x) {
    float4 v = ((const float4*)in)[i];
    short4 o;
    o.x = f2bf(v.x); o.y = f2bf(v.y); o.z = f2bf(v.z); o.w = f2bf(v.w);
    ((short4*)out)[i] = o;
  }
}

// ---------------- bf16 GEMM, B^T layout (N,K), f32 out + bias ----------------
// BK=64, XCD-contiguous 1D grid, involution chunk-XOR LDS swizzle.
__global__ __launch_bounds__(256) void gemm_bt_bias(
    const short* __restrict__ A, const short* __restrict__ B,
    const float* __restrict__ bias, float* __restrict__ C,
    int M, int N, int K) {
  __shared__ short As[128 * 64];
  __shared__ short Bs[128 * 64];
  int tid = threadIdx.x;
  int w = tid >> 6, l = tid & 63;
  int lrow = l & 15, lg = l >> 4;
  int bid = blockIdx.x;
  int cpx = gridDim.x >> 3;
  int lid = (bid & 7) * cpx + (bid >> 3);  // XCD-contiguous logical id
  int ntx = N >> 7;
  int m0 = (lid / ntx) * 128, n0 = (lid % ntx) * 128;
  int wm = w & 1, wn = w >> 1;

  f32x4 acc[4][4] = {};

  const char* Abase = (const char*)A + (size_t)m0 * K * 2;
  const char* Bbase = (const char*)B + (size_t)n0 * K * 2;

  for (int k0 = 0; k0 < K; k0 += 64) {
#pragma unroll
    for (int j = 0; j < 4; j++) {
      int c = j * 256 + tid;
      int row = c >> 3;
      int sc = c & 7;
      int slc = sc ^ (row & 7);  // stage-side involution swizzle
      size_t goff = (size_t)row * K * 2 + (size_t)k0 * 2 + slc * 16;
      int loff = (j * 256 + w * 64) * 16;  // wave-uniform LDS base
      gload_lds16(Abase + goff, (char*)As + loff);
      gload_lds16(Bbase + goff, (char*)Bs + loff);
    }
    __syncthreads();
#pragma unroll
    for (int kk = 0; kk < 2; kk++) {
      bf16x8 a[4], b[4];
#pragma unroll
      for (int mt = 0; mt < 4; mt++) {
        int row = wm * 64 + mt * 16 + lrow;
        int p = (kk * 4 + lg) ^ (row & 7);
        a[mt] = *(const bf16x8*)&As[row * 64 + p * 8];
      }
#pragma unroll
      for (int nt = 0; nt < 4; nt++) {
        int row = wn * 64 + nt * 16 + lrow;
        int p = (kk * 4 + lg) ^ (row & 7);
        b[nt] = *(const bf16x8*)&Bs[row * 64 + p * 8];
      }
#pragma unroll
      for (int mt = 0; mt < 4; mt++)
#pragma unroll
        for (int nt = 0; nt < 4; nt++)
          acc[mt][nt] = __builtin_amdgcn_mfma_f32_16x16x32_bf16(a[mt], b[nt], acc[mt][nt], 0, 0, 0);
    }
    __syncthreads();
  }
#pragma unroll
  for (int nt = 0; nt < 4; nt++) {
    int col = n0 + wn * 64 + nt * 16 + lrow;
    float bv = bias[col];
#pragma unroll
    for (int mt = 0; mt < 4; mt++) {
      int mrow = m0 + wm * 64 + mt * 16 + lg * 4;
#pragma unroll
      for (int r = 0; r < 4; r++)
        C[(size_t)(mrow + r) * N + col] = acc[mt][nt][r] + bv;
    }
  }
}

// ---------------- RoPE for q,k (f32 in, bf16 out, head-major, pad to 96) ----------------
// q additionally scaled by 80^-0.5 * log2(e) (softmax done in exp2 domain).
__global__ void rope_qk(const float* __restrict__ qkv, const float* __restrict__ cosb,
                        const float* __restrict__ sinb, short* __restrict__ qg,
                        short* __restrict__ kg) {
  int t = blockIdx.x * blockDim.x + threadIdx.x;
  if (t >= SEQ * NHEADS * 40) return;
  int d = t % 40;
  int h = (t / 40) & 15;
  int s = t / 640;
  const float* row = qkv + (size_t)s * (3 * DIM);
  float c0 = cosb[s * HD + d], c1 = cosb[s * HD + d + 40];
  float s0 = sinb[s * HD + d], s1 = sinb[s * HD + d + 40];
  float x1 = row[h * HD + d], x2 = row[h * HD + d + 40];
  float q0 = x1 * c0 - x2 * s0;
  float q1 = x2 * c1 + x1 * s1;
  float y1 = row[DIM + h * HD + d], y2 = row[DIM + h * HD + d + 40];
  float k0 = y1 * c0 - y2 * s0;
  float k1 = y2 * c1 + y1 * s1;
  const float sc = 0.11180339887498949f * 1.4426950408889634f;
  size_t base = ((size_t)h * SEQ + s) * HDP;
  qg[base + d] = f2bf(q0 * sc);
  qg[base + d + 40] = f2bf(q1 * sc);
  kg[base + d] = f2bf(k0);
  kg[base + d + 40] = f2bf(k1);
  if (d < 16) { qg[base + 80 + d] = 0; kg[base + 80 + d] = 0; }
}

// ---------------- V transpose: qkv f32 (S,3,H,80) -> vt bf16 (H,80,S) ----------------
__global__ void v_transpose(const float* __restrict__ qkv, short* __restrict__ vt) {
  __shared__ float T[16][68];
  int st = blockIdx.x, dt = blockIdx.y, h = blockIdx.z;
  int d0 = dt * 16, s0 = st * 64;
  int t = threadIdx.x;
  int dd = t & 15, ss = t >> 4;
#pragma unroll
  for (int j = 0; j < 4; j++) {
    int s = ss + j * 16;
    T[dd][s] = qkv[(size_t)(s0 + s) * (3 * DIM) + 2 * DIM + h * HD + d0 + dd];
  }
  __syncthreads();
  int s2 = t & 63, dr = t >> 6;
#pragma unroll
  for (int j = 0; j < 4; j++) {
    int d = dr + j * 4;
    vt[((size_t)(h * HD + d0 + d)) * SEQ + s0 + s2] = f2bf(T[d][s2]);
  }
}

// ---------------- flash attention v7 ----------------
// = v6, but __launch_bounds__(512, 2): hipcc treats the 2nd arg as min
// BLOCKS/CU (CUDA-style). (512,4) meant 32 waves/CU -> hard VGPR cap 64,
// which spilled the batched V fragments to scratch in r11/r12 (FETCH
// 457MB, WRITE 259MB). (512,2) -> cap 128, matching the LDS-bound
// occupancy (68KB -> 2 blocks/CU), so no occupancy loss and no spill.
__global__ __launch_bounds__(512, 2) void attn_kernel(
    const short* __restrict__ qg, const short* __restrict__ kg,
    const short* __restrict__ vt, short* __restrict__ out) {
  __shared__ short Ks[2][64 * 128];  // 32 KB (rows padded 96->128 shorts)
  __shared__ short Pl[8][32 * PST];  // 36 KB
  int bid = blockIdx.x;
  int b = bid & 7, h = (bid >> 3) & 15, qt = bid >> 7;
  int tid = threadIdx.x;
  int w = tid >> 6, l = tid & 63;
  int lrow = l & 15, lg = l >> 4;
  int qbase_s = b * SEG + qt * 256 + w * 32;

  const short* qh = qg + (size_t)h * SEQ * HDP;
  const short* kh = kg + (size_t)h * SEQ * HDP;
  const short* vh = vt + (size_t)h * HD * SEQ;

#define STAGE_K(BUF, KEY0N)                                                    \
  {                                                                            \
    _Pragma("unroll") for (int sr = 0; sr < 2; sr++) {                         \
      int sbase = sr * 512 + w * 64;                                           \
      int ss = sbase + l;                                                      \
      int skey = ss >> 4, sc = ss & 15;                                        \
      int slc = sc ^ (skey & 7);                                               \
      const short* ssrc =                                                      \
          kh + (size_t)((KEY0N) + skey) * HDP + (slc < 12 ? slc * 8 : 0);      \
      gload_lds16(ssrc, (char*)&Ks[BUF][0] + sbase * 16);                      \
    }                                                                          \
  }

  bf16x8 qf[2][3];
#pragma unroll
  for (int mt = 0; mt < 2; mt++)
#pragma unroll
    for (int ks = 0; ks < 3; ks++)
      qf[mt][ks] = *(const bf16x8*)&qh[(size_t)(qbase_s + mt * 16 + lrow) * HDP + ks * 32 + lg * 8];

  f32x4 o[2][5] = {};
  float m_st[2] = {-1e30f, -1e30f};
  float l_st[2] = {0.f, 0.f};

  short* Pw = &Pl[w][0];

  STAGE_K(0, b * SEG);
  __syncthreads();

  for (int i = 0; i < NSTEP; i++) {
    int cur = i & 1;
    int key0 = b * SEG + i * KVB;
    if (i + 1 < NSTEP) {
      STAGE_K(cur ^ 1, key0 + KVB);
    }

    // --- QK^T (swapped: mfma(K,Q), col=query, key in-lane) from LDS ---
    f32x4 sv[2][4] = {};
    __builtin_amdgcn_s_setprio(1);
#pragma unroll
    for (int kt = 0; kt < 4; kt++) {
      bf16x8 kf[3];
      int key = kt * 16 + lrow;
#pragma unroll
      for (int ks = 0; ks < 3; ks++) {
        int p = (ks * 4 + lg) ^ (key & 7);
        kf[ks] = *(const bf16x8*)&Ks[cur][key * 128 + p * 8];
      }
#pragma unroll
      for (int mt = 0; mt < 2; mt++)
#pragma unroll
        for (int ks = 0; ks < 3; ks++)
          sv[mt][kt] = __builtin_amdgcn_mfma_f32_16x16x32_bf16(kf[ks], qf[mt][ks], sv[mt][kt], 0, 0, 0);
    }
    __builtin_amdgcn_s_setprio(0);

    // --- V loads, batched here (no fence): latency overlaps softmax below ---
    bf16x8 vf[5][2];
#pragma unroll
    for (int nt = 0; nt < 5; nt++)
#pragma unroll
      for (int ks = 0; ks < 2; ks++)
        vf[nt][ks] = *(const bf16x8*)&vh[(size_t)(nt * 16 + lrow) * SEQ + key0 + ks * 32 + lg * 8];

    // --- per-query tile max: in-lane over 16 keys, then 2 shfl ---
    float cm[2];
#pragma unroll
    for (int mt = 0; mt < 2; mt++) {
      float a0 = fmaxf(fmaxf(sv[mt][0][0], sv[mt][0][1]), fmaxf(sv[mt][0][2], sv[mt][0][3]));
      float a1 = fmaxf(fmaxf(sv[mt][1][0], sv[mt][1][1]), fmaxf(sv[mt][1][2], sv[mt][1][3]));
      float a2 = fmaxf(fmaxf(sv[mt][2][0], sv[mt][2][1]), fmaxf(sv[mt][2][2], sv[mt][2][3]));
      float a3 = fmaxf(fmaxf(sv[mt][3][0], sv[mt][3][1]), fmaxf(sv[mt][3][2], sv[mt][3][3]));
      float c = fmaxf(fmaxf(a0, a1), fmaxf(a2, a3));
      c = fmaxf(c, __shfl_xor(c, 16));
      c = fmaxf(c, __shfl_xor(c, 32));
      cm[mt] = c;
    }
    // defer-max: rescale only when max grew by > 8 (log2 units)
    if (__any((cm[0] > m_st[0] + 8.f) || (cm[1] > m_st[1] + 8.f))) {
#pragma unroll
      for (int mt = 0; mt < 2; mt++) {
        float mn = fmaxf(m_st[mt], cm[mt]);
        float c = fast_exp2(m_st[mt] - mn);
        m_st[mt] = mn;
        l_st[mt] *= c;
        float cr[4];
#pragma unroll
        for (int r = 0; r < 4; r++) cr[r] = __shfl(c, lg * 4 + r);
#pragma unroll
        for (int nt = 0; nt < 5; nt++)
#pragma unroll
          for (int r = 0; r < 4; r++) o[mt][nt][r] *= cr[r];
      }
    }
    // p = exp2(s - m); accumulate l; packed cvt, one b64 LDS write per 4 keys
#pragma unroll
    for (int mt = 0; mt < 2; mt++) {
      float rs = 0.f;
#pragma unroll
      for (int kt = 0; kt < 4; kt++) {
#pragma unroll
        for (int r = 0; r < 4; r++) {
          sv[mt][kt][r] = fast_exp2(sv[mt][kt][r] - m_st[mt]);
          rs += sv[mt][kt][r];
        }
        uint2 pk;
        pk.x = cvt_pk_bf16(sv[mt][kt][0], sv[mt][kt][1]);
        pk.y = cvt_pk_bf16(sv[mt][kt][2], sv[mt][kt][3]);
        *(uint2*)&Pw[(mt * 16 + lrow) * PST + kt * 16 + lg * 4] = pk;
      }
      rs += __shfl_xor(rs, 16);
      rs += __shfl_xor(rs, 32);
      l_st[mt] += rs;
    }

    // --- PV ---
    bf16x8 pa[2][2];
#pragma unroll
    for (int mt = 0; mt < 2; mt++)
#pragma unroll
      for (int ks = 0; ks < 2; ks++)
        pa[mt][ks] = *(const bf16x8*)&Pw[(mt * 16 + lrow) * PST + ks * 32 + lg * 8];
    __builtin_amdgcn_s_setprio(1);
#pragma unroll
    for (int nt = 0; nt < 5; nt++)
#pragma unroll
      for (int mt = 0; mt < 2; mt++)
#pragma unroll
        for (int ks = 0; ks < 2; ks++)
          o[mt][nt] = __builtin_amdgcn_mfma_f32_16x16x32_bf16(pa[mt][ks], vf[nt][ks], o[mt][nt], 0, 0, 0);
    __builtin_amdgcn_s_setprio(0);

    __syncthreads();  // drain K stage; all QK reads of Ks[cur] done
  }

#pragma unroll
  for (int mt = 0; mt < 2; mt++) {
    float rl = 1.f / l_st[mt];
    float ir[4];
#pragma unroll
    for (int r = 0; r < 4; r++) ir[r] = __shfl(rl, lg * 4 + r);
#pragma unroll
    for (int r = 0; r < 4; r++) {
      int srow = qbase_s + mt * 16 + lg * 4 + r;
#pragma unroll
      for (int nt = 0; nt < 5; nt++)
        out[(size_t)srow * DIM + h * HD + nt * 16 + lrow] = f2bf(o[mt][nt][r] * ir[r]);
    }
  }
}

extern "C" void kernel_launch(void* const* d_in, const int* in_sizes, int n_in,
                              void* d_out, int out_size, void* d_ws, size_t ws_size,
                              hipStream_t stream) {
  const float* hidden = (const float*)d_in[0];
  const float* cosb = (const float*)d_in[1];
  const float* sinb = (const float*)d_in[2];
  const float* qkv_w = (const float*)d_in[3];
  const float* qkv_b = (const float*)d_in[4];
  const float* proj_w = (const float*)d_in[5];
  const float* proj_b = (const float*)d_in[6];

  char* ws = (char*)d_ws;
  float* qkv_f = (float*)(ws);
  short* attn_o = (short*)(ws);
  short* wp_bf = (short*)(ws + 23068672);
  short* q_bf = (short*)(ws + 125829120);
  short* k_bf = (short*)(ws + 150994944);
  short* v_tb = (short*)(ws + 176160768);
  short* h_bf = (short*)(ws + 197132288);
  short* wq_bf = (short*)(ws + 218103808);

  cast_f32_bf16<<<4096, 256, 0, stream>>>(hidden, h_bf, SEQ * DIM);
  cast_f32_bf16<<<4096, 256, 0, stream>>>(qkv_w, wq_bf, 3 * DIM * DIM);
  gemm_bt_bias<<<1920, 256, 0, stream>>>(h_bf, wq_bf, qkv_b, qkv_f, SEQ, 3 * DIM, DIM);
  rope_qk<<<20480, 256, 0, stream>>>(qkv_f, cosb, sinb, q_bf, k_bf);
  v_transpose<<<dim3(128, 5, 16), 256, 0, stream>>>(qkv_f, v_tb);
  cast_f32_bf16<<<2048, 256, 0, stream>>>(proj_w, wp_bf, DIM * DIM);
  attn_kernel<<<512, 512, 0, stream>>>(q_bf, k_bf, v_tb, attn_o);
  gemm_bt_bias<<<640, 256, 0, stream>>>(attn_o, wp_bf, proj_b, (float*)d_out, SEQ, DIM, DIM);
}

// Round 14
// 326.982 us; speedup vs baseline: 1.4397x; 1.0663x over previous
//
#include <hip/hip_runtime.h>

#define SEQ 8192
#define DIM 1280
#define NHEADS 16
#define HD 80
#define HDP 96
#define NSEG 8
#define SEG 1024
#define KVB 64
#define NSTEP (SEG / KVB)
#define PST 72

typedef float f32x4 __attribute__((ext_vector_type(4)));
typedef short bf16x8 __attribute__((ext_vector_type(8)));
typedef unsigned int u32;

__device__ __forceinline__ float fast_exp2(float x) {
  return __builtin_amdgcn_exp2f(x);
}

__device__ __forceinline__ short f2bf(float f) {
  unsigned int u = __builtin_bit_cast(unsigned int, f);
  u = (u + 0x7fff + ((u >> 16) & 1)) >> 16;
  return (short)u;
}

__device__ __forceinline__ float bf2f(short s) {
  u32 u = ((u32)(unsigned short)s) << 16;
  return __builtin_bit_cast(float, u);
}

// packed f32x2 -> bf16x2 (RNE), D.lo = S0, D.hi = S1. No builtin on gfx950.
__device__ __forceinline__ u32 cvt_pk_bf16(float lo, float hi) {
  u32 r;
  asm("v_cvt_pk_bf16_f32 %0, %1, %2" : "=v"(r) : "v"(lo), "v"(hi));
  return r;
}

typedef __attribute__((address_space(1))) const unsigned int glds_src_t;
typedef __attribute__((address_space(3))) unsigned int glds_dst_t;
__device__ __forceinline__ void gload_lds16(const void* g, void* l) {
  __builtin_amdgcn_global_load_lds((glds_src_t*)g, (glds_dst_t*)l, 16, 0, 0);
}

// ---------------- generic f32 -> bf16 cast (vectorized) ----------------
__global__ void cast_f32_bf16(const float* __restrict__ in, short* __restrict__ out, int n) {
  int n4 = n >> 2;
  for (int i = blockIdx.x * blockDim.x + threadIdx.x; i < n4; i += gridDim.x * blockDim.x) {
    float4 v = ((const float4*)in)[i];
    short4 o;
    o.x = f2bf(v.x); o.y = f2bf(v.y); o.z = f2bf(v.z); o.w = f2bf(v.w);
    ((short4*)out)[i] = o;
  }
}

// ---------------- bf16 GEMM, B^T layout (N,K), bias; f32 or bf16 out ----------------
// Stage-ahead DOUBLE-BUFFERED LDS, one barrier per K-step: loads for step
// i+1 are issued before the MFMA of step i, so L2 latency hides under
// compute (single-buffered version drained vmcnt(0) cold at each barrier:
// MfmaUtil 25%). BK=32 keeps LDS at 32 KB (2 bufs) — avoids the 64 KB
// occupancy cliff (m132). XCD-contiguous 1D grid; r9 involution swizzle
// (chunk ^ ((row>>1)&3)) on stage-source + ds_read side, 2-way max.
// If Cb != nullptr, output is bf16 to Cb, else f32 to C.
__global__ __launch_bounds__(256) void gemm_bt_bias(
    const short* __restrict__ A, const short* __restrict__ B,
    const float* __restrict__ bias, float* __restrict__ C,
    short* __restrict__ Cb, int M, int N, int K) {
  __shared__ short As[2][128 * 32];
  __shared__ short Bs[2][128 * 32];
  int tid = threadIdx.x;
  int w = tid >> 6, l = tid & 63;
  int lrow = l & 15, lg = l >> 4;
  int bid = blockIdx.x;
  int cpx = gridDim.x >> 3;
  int lid = (bid & 7) * cpx + (bid >> 3);  // XCD-contiguous logical id
  int ntx = N >> 7;
  int m0 = (lid / ntx) * 128, n0 = (lid % ntx) * 128;
  int wm = w & 1, wn = w >> 1;

  f32x4 acc[4][4] = {};

  const char* Abase = (const char*)A + (size_t)m0 * K * 2;
  const char* Bbase = (const char*)B + (size_t)n0 * K * 2;

#define STAGE_G(BUF, K0)                                                       \
  {                                                                            \
    _Pragma("unroll") for (int j = 0; j < 2; j++) {                            \
      int c = j * 256 + tid;                                                   \
      int row = c >> 2;                                                        \
      int slc = (c & 3) ^ ((row >> 1) & 3);                                    \
      size_t goff = (size_t)row * K * 2 + (size_t)(K0) * 2 + slc * 16;         \
      int loff = (j * 256 + w * 64) * 16;                                      \
      gload_lds16(Abase + goff, (char*)&As[BUF][0] + loff);                    \
      gload_lds16(Bbase + goff, (char*)&Bs[BUF][0] + loff);                    \
    }                                                                          \
  }

  STAGE_G(0, 0);
  __syncthreads();

  for (int k0 = 0; k0 < K; k0 += 32) {
    int cur = (k0 >> 5) & 1;
    if (k0 + 32 < K) {
      STAGE_G(cur ^ 1, k0 + 32);
    }
    bf16x8 a[4], b[4];
#pragma unroll
    for (int mt = 0; mt < 4; mt++) {
      int row = wm * 64 + mt * 16 + lrow;
      int p = lg ^ ((row >> 1) & 3);
      a[mt] = *(const bf16x8*)&As[cur][row * 32 + p * 8];
    }
#pragma unroll
    for (int nt = 0; nt < 4; nt++) {
      int row = wn * 64 + nt * 16 + lrow;
      int p = lg ^ ((row >> 1) & 3);
      b[nt] = *(const bf16x8*)&Bs[cur][row * 32 + p * 8];
    }
#pragma unroll
    for (int mt = 0; mt < 4; mt++)
#pragma unroll
      for (int nt = 0; nt < 4; nt++)
        acc[mt][nt] = __builtin_amdgcn_mfma_f32_16x16x32_bf16(a[mt], b[nt], acc[mt][nt], 0, 0, 0);
    __syncthreads();  // stage(cur^1) landed; all reads of As/Bs[cur] done
  }

#pragma unroll
  for (int nt = 0; nt < 4; nt++) {
    int col = n0 + wn * 64 + nt * 16 + lrow;
    float bv = bias[col];
#pragma unroll
    for (int mt = 0; mt < 4; mt++) {
      int mrow = m0 + wm * 64 + mt * 16 + lg * 4;
      if (Cb) {
#pragma unroll
        for (int r = 0; r < 4; r++)
          Cb[(size_t)(mrow + r) * N + col] = f2bf(acc[mt][nt][r] + bv);
      } else {
#pragma unroll
        for (int r = 0; r < 4; r++)
          C[(size_t)(mrow + r) * N + col] = acc[mt][nt][r] + bv;
      }
    }
  }
}

// ---------------- RoPE for q,k (bf16 in, bf16 out, head-major, pad to 96) ----------------
// q additionally scaled by 80^-0.5 * log2(e) (softmax done in exp2 domain).
__global__ void rope_qk(const short* __restrict__ qkv, const float* __restrict__ cosb,
                        const float* __restrict__ sinb, short* __restrict__ qg,
                        short* __restrict__ kg) {
  int t = blockIdx.x * blockDim.x + threadIdx.x;
  if (t >= SEQ * NHEADS * 40) return;
  int d = t % 40;
  int h = (t / 40) & 15;
  int s = t / 640;
  const short* row = qkv + (size_t)s * (3 * DIM);
  float c0 = cosb[s * HD + d], c1 = cosb[s * HD + d + 40];
  float s0 = sinb[s * HD + d], s1 = sinb[s * HD + d + 40];
  float x1 = bf2f(row[h * HD + d]), x2 = bf2f(row[h * HD + d + 40]);
  float q0 = x1 * c0 - x2 * s0;
  float q1 = x2 * c1 + x1 * s1;
  float y1 = bf2f(row[DIM + h * HD + d]), y2 = bf2f(row[DIM + h * HD + d + 40]);
  float k0 = y1 * c0 - y2 * s0;
  float k1 = y2 * c1 + y1 * s1;
  const float sc = 0.11180339887498949f * 1.4426950408889634f;
  size_t base = ((size_t)h * SEQ + s) * HDP;
  qg[base + d] = f2bf(q0 * sc);
  qg[base + d + 40] = f2bf(q1 * sc);
  kg[base + d] = f2bf(k0);
  kg[base + d + 40] = f2bf(k1);
  if (d < 16) { qg[base + 80 + d] = 0; kg[base + 80 + d] = 0; }
}

// ---------------- V transpose: qkv bf16 (S,3,H,80) -> vt bf16 (H,80,S) ----------------
__global__ void v_transpose(const short* __restrict__ qkv, short* __restrict__ vt) {
  __shared__ short T[16][72];
  int st = blockIdx.x, dt = blockIdx.y, h = blockIdx.z;
  int d0 = dt * 16, s0 = st * 64;
  int t = threadIdx.x;
  int dd = t & 15, ss = t >> 4;
#pragma unroll
  for (int j = 0; j < 4; j++) {
    int s = ss + j * 16;
    T[dd][s] = qkv[(size_t)(s0 + s) * (3 * DIM) + 2 * DIM + h * HD + d0 + dd];
  }
  __syncthreads();
  int s2 = t & 63, dr = t >> 6;
#pragma unroll
  for (int j = 0; j < 4; j++) {
    int d = dr + j * 4;
    vt[((size_t)(h * HD + d0 + d)) * SEQ + s0 + s2] = T[d][s2];
  }
}

// ---------------- flash attention v7 ----------------
// K-LDS coop staging (dbuf, 1 barrier/iter), cvt_pk P-pack, setprio,
// batched V loads after QK. __launch_bounds__(512, 2): hipcc's 2nd arg is
// min BLOCKS/CU — (512,4) capped VGPR at 64 and spilled (r11/r12).
__global__ __launch_bounds__(512, 2) void attn_kernel(
    const short* __restrict__ qg, const short* __restrict__ kg,
    const short* __restrict__ vt, short* __restrict__ out) {
  __shared__ short Ks[2][64 * 128];  // 32 KB (rows padded 96->128 shorts)
  __shared__ short Pl[8][32 * PST];  // 36 KB
  int bid = blockIdx.x;
  int b = bid & 7, h = (bid >> 3) & 15, qt = bid >> 7;
  int tid = threadIdx.x;
  int w = tid >> 6, l = tid & 63;
  int lrow = l & 15, lg = l >> 4;
  int qbase_s = b * SEG + qt * 256 + w * 32;

  const short* qh = qg + (size_t)h * SEQ * HDP;
  const short* kh = kg + (size_t)h * SEQ * HDP;
  const short* vh = vt + (size_t)h * HD * SEQ;

#define STAGE_K(BUF, KEY0N)                                                    \
  {                                                                            \
    _Pragma("unroll") for (int sr = 0; sr < 2; sr++) {                         \
      int sbase = sr * 512 + w * 64;                                           \
      int ss = sbase + l;                                                      \
      int skey = ss >> 4, sc = ss & 15;                                        \
      int slc = sc ^ (skey & 7);                                               \
      const short* ssrc =                                                      \
          kh + (size_t)((KEY0N) + skey) * HDP + (slc < 12 ? slc * 8 : 0);      \
      gload_lds16(ssrc, (char*)&Ks[BUF][0] + sbase * 16);                      \
    }                                                                          \
  }

  bf16x8 qf[2][3];
#pragma unroll
  for (int mt = 0; mt < 2; mt++)
#pragma unroll
    for (int ks = 0; ks < 3; ks++)
      qf[mt][ks] = *(const bf16x8*)&qh[(size_t)(qbase_s + mt * 16 + lrow) * HDP + ks * 32 + lg * 8];

  f32x4 o[2][5] = {};
  float m_st[2] = {-1e30f, -1e30f};
  float l_st[2] = {0.f, 0.f};

  short* Pw = &Pl[w][0];

  STAGE_K(0, b * SEG);
  __syncthreads();

  for (int i = 0; i < NSTEP; i++) {
    int cur = i & 1;
    int key0 = b * SEG + i * KVB;
    if (i + 1 < NSTEP) {
      STAGE_K(cur ^ 1, key0 + KVB);
    }

    // --- QK^T (swapped: mfma(K,Q), col=query, key in-lane) from LDS ---
    f32x4 sv[2][4] = {};
    __builtin_amdgcn_s_setprio(1);
#pragma unroll
    for (int kt = 0; kt < 4; kt++) {
      bf16x8 kf[3];
      int key = kt * 16 + lrow;
#pragma unroll
      for (int ks = 0; ks < 3; ks++) {
        int p = (ks * 4 + lg) ^ (key & 7);
        kf[ks] = *(const bf16x8*)&Ks[cur][key * 128 + p * 8];
      }
#pragma unroll
      for (int mt = 0; mt < 2; mt++)
#pragma unroll
        for (int ks = 0; ks < 3; ks++)
          sv[mt][kt] = __builtin_amdgcn_mfma_f32_16x16x32_bf16(kf[ks], qf[mt][ks], sv[mt][kt], 0, 0, 0);
    }
    __builtin_amdgcn_s_setprio(0);

    // --- V loads, batched here (no fence): latency overlaps softmax below ---
    bf16x8 vf[5][2];
#pragma unroll
    for (int nt = 0; nt < 5; nt++)
#pragma unroll
      for (int ks = 0; ks < 2; ks++)
        vf[nt][ks] = *(const bf16x8*)&vh[(size_t)(nt * 16 + lrow) * SEQ + key0 + ks * 32 + lg * 8];

    // --- per-query tile max: in-lane over 16 keys, then 2 shfl ---
    float cm[2];
#pragma unroll
    for (int mt = 0; mt < 2; mt++) {
      float a0 = fmaxf(fmaxf(sv[mt][0][0], sv[mt][0][1]), fmaxf(sv[mt][0][2], sv[mt][0][3]));
      float a1 = fmaxf(fmaxf(sv[mt][1][0], sv[mt][1][1]), fmaxf(sv[mt][1][2], sv[mt][1][3]));
      float a2 = fmaxf(fmaxf(sv[mt][2][0], sv[mt][2][1]), fmaxf(sv[mt][2][2], sv[mt][2][3]));
      float a3 = fmaxf(fmaxf(sv[mt][3][0], sv[mt][3][1]), fmaxf(sv[mt][3][2], sv[mt][3][3]));
      float c = fmaxf(fmaxf(a0, a1), fmaxf(a2, a3));
      c = fmaxf(c, __shfl_xor(c, 16));
      c = fmaxf(c, __shfl_xor(c, 32));
      cm[mt] = c;
    }
    // defer-max: rescale only when max grew by > 8 (log2 units)
    if (__any((cm[0] > m_st[0] + 8.f) || (cm[1] > m_st[1] + 8.f))) {
#pragma unroll
      for (int mt = 0; mt < 2; mt++) {
        float mn = fmaxf(m_st[mt], cm[mt]);
        float c = fast_exp2(m_st[mt] - mn);
        m_st[mt] = mn;
        l_st[mt] *= c;
        float cr[4];
#pragma unroll
        for (int r = 0; r < 4; r++) cr[r] = __shfl(c, lg * 4 + r);
#pragma unroll
        for (int nt = 0; nt < 5; nt++)
#pragma unroll
          for (int r = 0; r < 4; r++) o[mt][nt][r] *= cr[r];
      }
    }
    // p = exp2(s - m); accumulate l; packed cvt, one b64 LDS write per 4 keys
#pragma unroll
    for (int mt = 0; mt < 2; mt++) {
      float rs = 0.f;
#pragma unroll
      for (int kt = 0; kt < 4; kt++) {
#pragma unroll
        for (int r = 0; r < 4; r++) {
          sv[mt][kt][r] = fast_exp2(sv[mt][kt][r] - m_st[mt]);
          rs += sv[mt][kt][r];
        }
        uint2 pk;
        pk.x = cvt_pk_bf16(sv[mt][kt][0], sv[mt][kt][1]);
        pk.y = cvt_pk_bf16(sv[mt][kt][2], sv[mt][kt][3]);
        *(uint2*)&Pw[(mt * 16 + lrow) * PST + kt * 16 + lg * 4] = pk;
      }
      rs += __shfl_xor(rs, 16);
      rs += __shfl_xor(rs, 32);
      l_st[mt] += rs;
    }

    // --- PV ---
    bf16x8 pa[2][2];
#pragma unroll
    for (int mt = 0; mt < 2; mt++)
#pragma unroll
      for (int ks = 0; ks < 2; ks++)
        pa[mt][ks] = *(const bf16x8*)&Pw[(mt * 16 + lrow) * PST + ks * 32 + lg * 8];
    __builtin_amdgcn_s_setprio(1);
#pragma unroll
    for (int nt = 0; nt < 5; nt++)
#pragma unroll
      for (int mt = 0; mt < 2; mt++)
#pragma unroll
        for (int ks = 0; ks < 2; ks++)
          o[mt][nt] = __builtin_amdgcn_mfma_f32_16x16x32_bf16(pa[mt][ks], vf[nt][ks], o[mt][nt], 0, 0, 0);
    __builtin_amdgcn_s_setprio(0);

    __syncthreads();  // drain K stage; all QK reads of Ks[cur] done
  }

#pragma unroll
  for (int mt = 0; mt < 2; mt++) {
    float rl = 1.f / l_st[mt];
    float ir[4];
#pragma unroll
    for (int r = 0; r < 4; r++) ir[r] = __shfl(rl, lg * 4 + r);
#pragma unroll
    for (int r = 0; r < 4; r++) {
      int srow = qbase_s + mt * 16 + lg * 4 + r;
#pragma unroll
      for (int nt = 0; nt < 5; nt++)
        out[(size_t)srow * DIM + h * HD + nt * 16 + lrow] = f2bf(o[mt][nt][r] * ir[r]);
    }
  }
}

extern "C" void kernel_launch(void* const* d_in, const int* in_sizes, int n_in,
                              void* d_out, int out_size, void* d_ws, size_t ws_size,
                              hipStream_t stream) {
  const float* hidden = (const float*)d_in[0];
  const float* cosb = (const float*)d_in[1];
  const float* sinb = (const float*)d_in[2];
  const float* qkv_w = (const float*)d_in[3];
  const float* qkv_b = (const float*)d_in[4];
  const float* proj_w = (const float*)d_in[5];
  const float* proj_b = (const float*)d_in[6];

  char* ws = (char*)d_ws;
  short* qkv_bf = (short*)(ws);                    // (S,3840) bf16 = 63 MB
  short* attn_o = (short*)(ws);                    // alias (qkv dead by attn)
  short* wp_bf = (short*)(ws + 23068672);          // after attn_o end (21 MB)
  short* q_bf = (short*)(ws + 125829120);
  short* k_bf = (short*)(ws + 150994944);
  short* v_tb = (short*)(ws + 176160768);
  short* h_bf = (short*)(ws + 197132288);
  short* wq_bf = (short*)(ws + 218103808);

  cast_f32_bf16<<<4096, 256, 0, stream>>>(hidden, h_bf, SEQ * DIM);
  cast_f32_bf16<<<4096, 256, 0, stream>>>(qkv_w, wq_bf, 3 * DIM * DIM);
  gemm_bt_bias<<<1920, 256, 0, stream>>>(h_bf, wq_bf, qkv_b, nullptr, qkv_bf, SEQ, 3 * DIM, DIM);
  rope_qk<<<20480, 256, 0, stream>>>(qkv_bf, cosb, sinb, q_bf, k_bf);
  v_transpose<<<dim3(128, 5, 16), 256, 0, stream>>>(qkv_bf, v_tb);
  cast_f32_bf16<<<2048, 256, 0, stream>>>(proj_w, wp_bf, DIM * DIM);
  attn_kernel<<<512, 512, 0, stream>>>(q_bf, k_bf, v_tb, attn_o);
  gemm_bt_bias<<<640, 256, 0, stream>>>(attn_o, wp_bf, proj_b, (float*)d_out, nullptr, SEQ, DIM, DIM);
}

// Round 15
// 321.728 us; speedup vs baseline: 1.4632x; 1.0163x over previous
//
#include <hip/hip_runtime.h>

#define SEQ 8192
#define DIM 1280
#define NHEADS 16
#define HD 80
#define HDP 96
#define NSEG 8
#define SEG 1024
#define KVB 64
#define NSTEP (SEG / KVB)
#define PST 72

typedef float f32x4 __attribute__((ext_vector_type(4)));
typedef short bf16x8 __attribute__((ext_vector_type(8)));
typedef unsigned int u32;

__device__ __forceinline__ float fast_exp2(float x) {
  return __builtin_amdgcn_exp2f(x);
}

__device__ __forceinline__ short f2bf(float f) {
  unsigned int u = __builtin_bit_cast(unsigned int, f);
  u = (u + 0x7fff + ((u >> 16) & 1)) >> 16;
  return (short)u;
}

__device__ __forceinline__ float bf2f(short s) {
  u32 u = ((u32)(unsigned short)s) << 16;
  return __builtin_bit_cast(float, u);
}

// packed f32x2 -> bf16x2 (RNE), D.lo = S0, D.hi = S1. No builtin on gfx950.
__device__ __forceinline__ u32 cvt_pk_bf16(float lo, float hi) {
  u32 r;
  asm("v_cvt_pk_bf16_f32 %0, %1, %2" : "=v"(r) : "v"(lo), "v"(hi));
  return r;
}

typedef __attribute__((address_space(1))) const unsigned int glds_src_t;
typedef __attribute__((address_space(3))) unsigned int glds_dst_t;
__device__ __forceinline__ void gload_lds16(const void* g, void* l) {
  __builtin_amdgcn_global_load_lds((glds_src_t*)g, (glds_dst_t*)l, 16, 0, 0);
}

// ---------------- generic f32 -> bf16 cast (vectorized) ----------------
__global__ void cast_f32_bf16(const float* __restrict__ in, short* __restrict__ out, int n) {
  int n4 = n >> 2;
  for (int i = blockIdx.x * blockDim.x + threadIdx.x; i < n4; i += gridDim.x * blockDim.x) {
    float4 v = ((const float4*)in)[i];
    short4 o;
    o.x = f2bf(v.x); o.y = f2bf(v.y); o.z = f2bf(v.z); o.w = f2bf(v.w);
    ((short4*)out)[i] = o;
  }
}

// ---------------- bf16 GEMM, B^T layout (N,K), bias; f32 or bf16 out ----------------
// BK=64 + stage-ahead DOUBLE-BUFFER (64 KB LDS, 2 blocks/CU): one
// vmcnt-drain barrier per 32 MFMA, and the drain is covered by the full
// MFMA phase (stage for step i+1 issued before compute of step i).
// r13 (single-buf BK=64): same drain rate, zero cover -> MfmaUtil 25%.
// r14 (dbuf BK=32): cover but 2x drain rate -> MfmaUtil 23%.
// XCD-contiguous 1D grid; involution swizzle chunk^(row&7) on stage source
// + ds_read side (2-way max bank aliasing).
// If Cb != nullptr, output is bf16 to Cb, else f32 to C.
__global__ __launch_bounds__(256) void gemm_bt_bias(
    const short* __restrict__ A, const short* __restrict__ B,
    const float* __restrict__ bias, float* __restrict__ C,
    short* __restrict__ Cb, int M, int N, int K) {
  __shared__ short As[2][128 * 64];  // 32 KB
  __shared__ short Bs[2][128 * 64];  // 32 KB
  int tid = threadIdx.x;
  int w = tid >> 6, l = tid & 63;
  int lrow = l & 15, lg = l >> 4;
  int bid = blockIdx.x;
  int cpx = gridDim.x >> 3;
  int lid = (bid & 7) * cpx + (bid >> 3);  // XCD-contiguous logical id
  int ntx = N >> 7;
  int m0 = (lid / ntx) * 128, n0 = (lid % ntx) * 128;
  int wm = w & 1, wn = w >> 1;

  f32x4 acc[4][4] = {};

  const char* Abase = (const char*)A + (size_t)m0 * K * 2;
  const char* Bbase = (const char*)B + (size_t)n0 * K * 2;

#define STAGE_G(BUF, K0)                                                       \
  {                                                                            \
    _Pragma("unroll") for (int j = 0; j < 4; j++) {                            \
      int c = j * 256 + tid;                                                   \
      int row = c >> 3;                                                        \
      int slc = (c & 7) ^ (row & 7);                                           \
      size_t goff = (size_t)row * K * 2 + (size_t)(K0) * 2 + slc * 16;         \
      int loff = (j * 256 + w * 64) * 16;                                      \
      gload_lds16(Abase + goff, (char*)&As[BUF][0] + loff);                    \
      gload_lds16(Bbase + goff, (char*)&Bs[BUF][0] + loff);                    \
    }                                                                          \
  }

  STAGE_G(0, 0);
  __syncthreads();

  for (int k0 = 0; k0 < K; k0 += 64) {
    int cur = (k0 >> 6) & 1;
    if (k0 + 64 < K) {
      STAGE_G(cur ^ 1, k0 + 64);  // issued BEFORE compute: full-phase cover
    }
#pragma unroll
    for (int kk = 0; kk < 2; kk++) {
      bf16x8 a[4], b[4];
#pragma unroll
      for (int mt = 0; mt < 4; mt++) {
        int row = wm * 64 + mt * 16 + lrow;
        int p = (kk * 4 + lg) ^ (row & 7);
        a[mt] = *(const bf16x8*)&As[cur][row * 64 + p * 8];
      }
#pragma unroll
      for (int nt = 0; nt < 4; nt++) {
        int row = wn * 64 + nt * 16 + lrow;
        int p = (kk * 4 + lg) ^ (row & 7);
        b[nt] = *(const bf16x8*)&Bs[cur][row * 64 + p * 8];
      }
#pragma unroll
      for (int mt = 0; mt < 4; mt++)
#pragma unroll
        for (int nt = 0; nt < 4; nt++)
          acc[mt][nt] = __builtin_amdgcn_mfma_f32_16x16x32_bf16(a[mt], b[nt], acc[mt][nt], 0, 0, 0);
    }
    __syncthreads();  // stage(cur^1) landed; all reads of As/Bs[cur] done
  }

#pragma unroll
  for (int nt = 0; nt < 4; nt++) {
    int col = n0 + wn * 64 + nt * 16 + lrow;
    float bv = bias[col];
#pragma unroll
    for (int mt = 0; mt < 4; mt++) {
      int mrow = m0 + wm * 64 + mt * 16 + lg * 4;
      if (Cb) {
#pragma unroll
        for (int r = 0; r < 4; r++)
          Cb[(size_t)(mrow + r) * N + col] = f2bf(acc[mt][nt][r] + bv);
      } else {
#pragma unroll
        for (int r = 0; r < 4; r++)
          C[(size_t)(mrow + r) * N + col] = acc[mt][nt][r] + bv;
      }
    }
  }
}

// ---------------- RoPE for q,k (bf16 in, bf16 out, head-major, pad to 96) ----------------
// q additionally scaled by 80^-0.5 * log2(e) (softmax done in exp2 domain).
__global__ void rope_qk(const short* __restrict__ qkv, const float* __restrict__ cosb,
                        const float* __restrict__ sinb, short* __restrict__ qg,
                        short* __restrict__ kg) {
  int t = blockIdx.x * blockDim.x + threadIdx.x;
  if (t >= SEQ * NHEADS * 40) return;
  int d = t % 40;
  int h = (t / 40) & 15;
  int s = t / 640;
  const short* row = qkv + (size_t)s * (3 * DIM);
  float c0 = cosb[s * HD + d], c1 = cosb[s * HD + d + 40];
  float s0 = sinb[s * HD + d], s1 = sinb[s * HD + d + 40];
  float x1 = bf2f(row[h * HD + d]), x2 = bf2f(row[h * HD + d + 40]);
  float q0 = x1 * c0 - x2 * s0;
  float q1 = x2 * c1 + x1 * s1;
  float y1 = bf2f(row[DIM + h * HD + d]), y2 = bf2f(row[DIM + h * HD + d + 40]);
  float k0 = y1 * c0 - y2 * s0;
  float k1 = y2 * c1 + y1 * s1;
  const float sc = 0.11180339887498949f * 1.4426950408889634f;
  size_t base = ((size_t)h * SEQ + s) * HDP;
  qg[base + d] = f2bf(q0 * sc);
  qg[base + d + 40] = f2bf(q1 * sc);
  kg[base + d] = f2bf(k0);
  kg[base + d + 40] = f2bf(k1);
  if (d < 16) { qg[base + 80 + d] = 0; kg[base + 80 + d] = 0; }
}

// ---------------- V transpose: qkv bf16 (S,3,H,80) -> vt bf16 (H,80,S) ----------------
__global__ void v_transpose(const short* __restrict__ qkv, short* __restrict__ vt) {
  __shared__ short T[16][72];
  int st = blockIdx.x, dt = blockIdx.y, h = blockIdx.z;
  int d0 = dt * 16, s0 = st * 64;
  int t = threadIdx.x;
  int dd = t & 15, ss = t >> 4;
#pragma unroll
  for (int j = 0; j < 4; j++) {
    int s = ss + j * 16;
    T[dd][s] = qkv[(size_t)(s0 + s) * (3 * DIM) + 2 * DIM + h * HD + d0 + dd];
  }
  __syncthreads();
  int s2 = t & 63, dr = t >> 6;
#pragma unroll
  for (int j = 0; j < 4; j++) {
    int d = dr + j * 4;
    vt[((size_t)(h * HD + d0 + d)) * SEQ + s0 + s2] = T[d][s2];
  }
}

// ---------------- flash attention v7 ----------------
// K-LDS coop staging (dbuf, 1 barrier/iter), cvt_pk P-pack, setprio,
// batched V loads after QK. __launch_bounds__(512, 2): hipcc's 2nd arg is
// min BLOCKS/CU — (512,4) capped VGPR at 64 and spilled (r11/r12).
__global__ __launch_bounds__(512, 2) void attn_kernel(
    const short* __restrict__ qg, const short* __restrict__ kg,
    const short* __restrict__ vt, short* __restrict__ out) {
  __shared__ short Ks[2][64 * 128];  // 32 KB (rows padded 96->128 shorts)
  __shared__ short Pl[8][32 * PST];  // 36 KB
  int bid = blockIdx.x;
  int b = bid & 7, h = (bid >> 3) & 15, qt = bid >> 7;
  int tid = threadIdx.x;
  int w = tid >> 6, l = tid & 63;
  int lrow = l & 15, lg = l >> 4;
  int qbase_s = b * SEG + qt * 256 + w * 32;

  const short* qh = qg + (size_t)h * SEQ * HDP;
  const short* kh = kg + (size_t)h * SEQ * HDP;
  const short* vh = vt + (size_t)h * HD * SEQ;

#define STAGE_K(BUF, KEY0N)                                                    \
  {                                                                            \
    _Pragma("unroll") for (int sr = 0; sr < 2; sr++) {                         \
      int sbase = sr * 512 + w * 64;                                           \
      int ss = sbase + l;                                                      \
      int skey = ss >> 4, sc = ss & 15;                                        \
      int slc = sc ^ (skey & 7);                                               \
      const short* ssrc =                                                      \
          kh + (size_t)((KEY0N) + skey) * HDP + (slc < 12 ? slc * 8 : 0);      \
      gload_lds16(ssrc, (char*)&Ks[BUF][0] + sbase * 16);                      \
    }                                                                          \
  }

  bf16x8 qf[2][3];
#pragma unroll
  for (int mt = 0; mt < 2; mt++)
#pragma unroll
    for (int ks = 0; ks < 3; ks++)
      qf[mt][ks] = *(const bf16x8*)&qh[(size_t)(qbase_s + mt * 16 + lrow) * HDP + ks * 32 + lg * 8];

  f32x4 o[2][5] = {};
  float m_st[2] = {-1e30f, -1e30f};
  float l_st[2] = {0.f, 0.f};

  short* Pw = &Pl[w][0];

  STAGE_K(0, b * SEG);
  __syncthreads();

  for (int i = 0; i < NSTEP; i++) {
    int cur = i & 1;
    int key0 = b * SEG + i * KVB;
    if (i + 1 < NSTEP) {
      STAGE_K(cur ^ 1, key0 + KVB);
    }

    // --- QK^T (swapped: mfma(K,Q), col=query, key in-lane) from LDS ---
    f32x4 sv[2][4] = {};
    __builtin_amdgcn_s_setprio(1);
#pragma unroll
    for (int kt = 0; kt < 4; kt++) {
      bf16x8 kf[3];
      int key = kt * 16 + lrow;
#pragma unroll
      for (int ks = 0; ks < 3; ks++) {
        int p = (ks * 4 + lg) ^ (key & 7);
        kf[ks] = *(const bf16x8*)&Ks[cur][key * 128 + p * 8];
      }
#pragma unroll
      for (int mt = 0; mt < 2; mt++)
#pragma unroll
        for (int ks = 0; ks < 3; ks++)
          sv[mt][kt] = __builtin_amdgcn_mfma_f32_16x16x32_bf16(kf[ks], qf[mt][ks], sv[mt][kt], 0, 0, 0);
    }
    __builtin_amdgcn_s_setprio(0);

    // --- V loads, batched here (no fence): latency overlaps softmax below ---
    bf16x8 vf[5][2];
#pragma unroll
    for (int nt = 0; nt < 5; nt++)
#pragma unroll
      for (int ks = 0; ks < 2; ks++)
        vf[nt][ks] = *(const bf16x8*)&vh[(size_t)(nt * 16 + lrow) * SEQ + key0 + ks * 32 + lg * 8];

    // --- per-query tile max: in-lane over 16 keys, then 2 shfl ---
    float cm[2];
#pragma unroll
    for (int mt = 0; mt < 2; mt++) {
      float a0 = fmaxf(fmaxf(sv[mt][0][0], sv[mt][0][1]), fmaxf(sv[mt][0][2], sv[mt][0][3]));
      float a1 = fmaxf(fmaxf(sv[mt][1][0], sv[mt][1][1]), fmaxf(sv[mt][1][2], sv[mt][1][3]));
      float a2 = fmaxf(fmaxf(sv[mt][2][0], sv[mt][2][1]), fmaxf(sv[mt][2][2], sv[mt][2][3]));
      float a3 = fmaxf(fmaxf(sv[mt][3][0], sv[mt][3][1]), fmaxf(sv[mt][3][2], sv[mt][3][3]));
      float c = fmaxf(fmaxf(a0, a1), fmaxf(a2, a3));
      c = fmaxf(c, __shfl_xor(c, 16));
      c = fmaxf(c, __shfl_xor(c, 32));
      cm[mt] = c;
    }
    // defer-max: rescale only when max grew by > 8 (log2 units)
    if (__any((cm[0] > m_st[0] + 8.f) || (cm[1] > m_st[1] + 8.f))) {
#pragma unroll
      for (int mt = 0; mt < 2; mt++) {
        float mn = fmaxf(m_st[mt], cm[mt]);
        float c = fast_exp2(m_st[mt] - mn);
        m_st[mt] = mn;
        l_st[mt] *= c;
        float cr[4];
#pragma unroll
        for (int r = 0; r < 4; r++) cr[r] = __shfl(c, lg * 4 + r);
#pragma unroll
        for (int nt = 0; nt < 5; nt++)
#pragma unroll
          for (int r = 0; r < 4; r++) o[mt][nt][r] *= cr[r];
      }
    }
    // p = exp2(s - m); accumulate l; packed cvt, one b64 LDS write per 4 keys
#pragma unroll
    for (int mt = 0; mt < 2; mt++) {
      float rs = 0.f;
#pragma unroll
      for (int kt = 0; kt < 4; kt++) {
#pragma unroll
        for (int r = 0; r < 4; r++) {
          sv[mt][kt][r] = fast_exp2(sv[mt][kt][r] - m_st[mt]);
          rs += sv[mt][kt][r];
        }
        uint2 pk;
        pk.x = cvt_pk_bf16(sv[mt][kt][0], sv[mt][kt][1]);
        pk.y = cvt_pk_bf16(sv[mt][kt][2], sv[mt][kt][3]);
        *(uint2*)&Pw[(mt * 16 + lrow) * PST + kt * 16 + lg * 4] = pk;
      }
      rs += __shfl_xor(rs, 16);
      rs += __shfl_xor(rs, 32);
      l_st[mt] += rs;
    }

    // --- PV ---
    bf16x8 pa[2][2];
#pragma unroll
    for (int mt = 0; mt < 2; mt++)
#pragma unroll
      for (int ks = 0; ks < 2; ks++)
        pa[mt][ks] = *(const bf16x8*)&Pw[(mt * 16 + lrow) * PST + ks * 32 + lg * 8];
    __builtin_amdgcn_s_setprio(1);
#pragma unroll
    for (int nt = 0; nt < 5; nt++)
#pragma unroll
      for (int mt = 0; mt < 2; mt++)
#pragma unroll
        for (int ks = 0; ks < 2; ks++)
          o[mt][nt] = __builtin_amdgcn_mfma_f32_16x16x32_bf16(pa[mt][ks], vf[nt][ks], o[mt][nt], 0, 0, 0);
    __builtin_amdgcn_s_setprio(0);

    __syncthreads();  // drain K stage; all QK reads of Ks[cur] done
  }

#pragma unroll
  for (int mt = 0; mt < 2; mt++) {
    float rl = 1.f / l_st[mt];
    float ir[4];
#pragma unroll
    for (int r = 0; r < 4; r++) ir[r] = __shfl(rl, lg * 4 + r);
#pragma unroll
    for (int r = 0; r < 4; r++) {
      int srow = qbase_s + mt * 16 + lg * 4 + r;
#pragma unroll
      for (int nt = 0; nt < 5; nt++)
        out[(size_t)srow * DIM + h * HD + nt * 16 + lrow] = f2bf(o[mt][nt][r] * ir[r]);
    }
  }
}

extern "C" void kernel_launch(void* const* d_in, const int* in_sizes, int n_in,
                              void* d_out, int out_size, void* d_ws, size_t ws_size,
                              hipStream_t stream) {
  const float* hidden = (const float*)d_in[0];
  const float* cosb = (const float*)d_in[1];
  const float* sinb = (const float*)d_in[2];
  const float* qkv_w = (const float*)d_in[3];
  const float* qkv_b = (const float*)d_in[4];
  const float* proj_w = (const float*)d_in[5];
  const float* proj_b = (const float*)d_in[6];

  char* ws = (char*)d_ws;
  short* qkv_bf = (short*)(ws);                    // (S,3840) bf16 = 63 MB
  short* attn_o = (short*)(ws);                    // alias (qkv dead by attn)
  short* wp_bf = (short*)(ws + 23068672);          // after attn_o end (21 MB)
  short* q_bf = (short*)(ws + 125829120);
  short* k_bf = (short*)(ws + 150994944);
  short* v_tb = (short*)(ws + 176160768);
  short* h_bf = (short*)(ws + 197132288);
  short* wq_bf = (short*)(ws + 218103808);

  cast_f32_bf16<<<4096, 256, 0, stream>>>(hidden, h_bf, SEQ * DIM);
  cast_f32_bf16<<<4096, 256, 0, stream>>>(qkv_w, wq_bf, 3 * DIM * DIM);
  gemm_bt_bias<<<1920, 256, 0, stream>>>(h_bf, wq_bf, qkv_b, nullptr, qkv_bf, SEQ, 3 * DIM, DIM);
  rope_qk<<<20480, 256, 0, stream>>>(qkv_bf, cosb, sinb, q_bf, k_bf);
  v_transpose<<<dim3(128, 5, 16), 256, 0, stream>>>(qkv_bf, v_tb);
  cast_f32_bf16<<<2048, 256, 0, stream>>>(proj_w, wp_bf, DIM * DIM);
  attn_kernel<<<512, 512, 0, stream>>>(q_bf, k_bf, v_tb, attn_o);
  gemm_bt_bias<<<640, 256, 0, stream>>>(attn_o, wp_bf, proj_b, (float*)d_out, nullptr, SEQ, DIM, DIM);
}

// Round 16
// 316.183 us; speedup vs baseline: 1.4889x; 1.0175x over previous
//
#include <hip/hip_runtime.h>

#define SEQ 8192
#define DIM 1280
#define NHEADS 16
#define HD 80
#define HDP 96
#define NSEG 8
#define SEG 1024
#define KVB 64
#define NSTEP (SEG / KVB)
#define PST 72

typedef float f32x4 __attribute__((ext_vector_type(4)));
typedef short bf16x8 __attribute__((ext_vector_type(8)));
typedef unsigned int u32;

__device__ __forceinline__ float fast_exp2(float x) {
  return __builtin_amdgcn_exp2f(x);
}

__device__ __forceinline__ short f2bf(float f) {
  unsigned int u = __builtin_bit_cast(unsigned int, f);
  u = (u + 0x7fff + ((u >> 16) & 1)) >> 16;
  return (short)u;
}

__device__ __forceinline__ float bf2f(short s) {
  u32 u = ((u32)(unsigned short)s) << 16;
  return __builtin_bit_cast(float, u);
}

// packed f32x2 -> bf16x2 (RNE), D.lo = S0, D.hi = S1. No builtin on gfx950.
__device__ __forceinline__ u32 cvt_pk_bf16(float lo, float hi) {
  u32 r;
  asm("v_cvt_pk_bf16_f32 %0, %1, %2" : "=v"(r) : "v"(lo), "v"(hi));
  return r;
}

typedef __attribute__((address_space(1))) const unsigned int glds_src_t;
typedef __attribute__((address_space(3))) unsigned int glds_dst_t;
__device__ __forceinline__ void gload_lds16(const void* g, void* l) {
  __builtin_amdgcn_global_load_lds((glds_src_t*)g, (glds_dst_t*)l, 16, 0, 0);
}

// ---------------- generic f32 -> bf16 cast (vectorized) ----------------
__global__ void cast_f32_bf16(const float* __restrict__ in, short* __restrict__ out, int n) {
  int n4 = n >> 2;
  for (int i = blockIdx.x * blockDim.x + threadIdx.x; i < n4; i += gridDim.x * blockDim.x) {
    float4 v = ((const float4*)in)[i];
    short4 o;
    o.x = f2bf(v.x); o.y = f2bf(v.y); o.z = f2bf(v.z); o.w = f2bf(v.w);
    ((short4*)out)[i] = o;
  }
}

// ---------------- bf16 GEMM, B^T layout (N,K), bias; f32 or bf16 out ----------------
// BK=64 dbuf + T4 COUNTED VMCNT: stage for step i+1 is issued, then
// s_waitcnt vmcnt(8) waits only for step i's loads (issued one full
// iteration ago — latency long covered), and the 8 new loads stay in
// flight ACROSS the barrier. r15's __syncthreads drained vmcnt(0) — i.e.
// waited for the JUST-issued stage with only ~300cy of MFMA cover vs
// ~600cy L3 latency (B panel 9.8MB > 4MB XCD L2) -> ~300cy exposed/step.
// Barrier A (after vmcnt): buf[cur] fully populated across waves.
// Barrier B (after compute): all reads done before buf[cur] restaged.
// XCD-contiguous 1D grid; involution swizzle chunk^(row&7), 2-way max.
// If Cb != nullptr, output is bf16 to Cb, else f32 to C.
__global__ __launch_bounds__(256) void gemm_bt_bias(
    const short* __restrict__ A, const short* __restrict__ B,
    const float* __restrict__ bias, float* __restrict__ C,
    short* __restrict__ Cb, int M, int N, int K) {
  __shared__ short As[2][128 * 64];  // 32 KB
  __shared__ short Bs[2][128 * 64];  // 32 KB
  int tid = threadIdx.x;
  int w = tid >> 6, l = tid & 63;
  int lrow = l & 15, lg = l >> 4;
  int bid = blockIdx.x;
  int cpx = gridDim.x >> 3;
  int lid = (bid & 7) * cpx + (bid >> 3);  // XCD-contiguous logical id
  int ntx = N >> 7;
  int m0 = (lid / ntx) * 128, n0 = (lid % ntx) * 128;
  int wm = w & 1, wn = w >> 1;

  f32x4 acc[4][4] = {};

  const char* Abase = (const char*)A + (size_t)m0 * K * 2;
  const char* Bbase = (const char*)B + (size_t)n0 * K * 2;

#define STAGE_G(BUF, K0)                                                       \
  {                                                                            \
    _Pragma("unroll") for (int j = 0; j < 4; j++) {                            \
      int c = j * 256 + tid;                                                   \
      int row = c >> 3;                                                        \
      int slc = (c & 7) ^ (row & 7);                                           \
      size_t goff = (size_t)row * K * 2 + (size_t)(K0) * 2 + slc * 16;         \
      int loff = (j * 256 + w * 64) * 16;                                      \
      gload_lds16(Abase + goff, (char*)&As[BUF][0] + loff);                    \
      gload_lds16(Bbase + goff, (char*)&Bs[BUF][0] + loff);                    \
    }                                                                          \
  }

  STAGE_G(0, 0);
  asm volatile("s_waitcnt vmcnt(0)" ::: "memory");
  __builtin_amdgcn_s_barrier();
  asm volatile("" ::: "memory");

  for (int k0 = 0; k0 < K; k0 += 64) {
    int cur = (k0 >> 6) & 1;
    if (k0 + 64 < K) {
      STAGE_G(cur ^ 1, k0 + 64);
      // wait only for the PREVIOUS stage's 8 loads; the 8 just issued
      // remain in flight across the barrier (T4 counted vmcnt).
      asm volatile("s_waitcnt vmcnt(8)" ::: "memory");
    } else {
      asm volatile("s_waitcnt vmcnt(0)" ::: "memory");
    }
    __builtin_amdgcn_s_barrier();  // A: buf[cur] populated by all waves
    asm volatile("" ::: "memory");
#pragma unroll
    for (int kk = 0; kk < 2; kk++) {
      bf16x8 a[4], b[4];
#pragma unroll
      for (int mt = 0; mt < 4; mt++) {
        int row = wm * 64 + mt * 16 + lrow;
        int p = (kk * 4 + lg) ^ (row & 7);
        a[mt] = *(const bf16x8*)&As[cur][row * 64 + p * 8];
      }
#pragma unroll
      for (int nt = 0; nt < 4; nt++) {
        int row = wn * 64 + nt * 16 + lrow;
        int p = (kk * 4 + lg) ^ (row & 7);
        b[nt] = *(const bf16x8*)&Bs[cur][row * 64 + p * 8];
      }
#pragma unroll
      for (int mt = 0; mt < 4; mt++)
#pragma unroll
        for (int nt = 0; nt < 4; nt++)
          acc[mt][nt] = __builtin_amdgcn_mfma_f32_16x16x32_bf16(a[mt], b[nt], acc[mt][nt], 0, 0, 0);
    }
    __builtin_amdgcn_s_barrier();  // B: reads of buf[cur] done before restage
    asm volatile("" ::: "memory");
  }

#pragma unroll
  for (int nt = 0; nt < 4; nt++) {
    int col = n0 + wn * 64 + nt * 16 + lrow;
    float bv = bias[col];
#pragma unroll
    for (int mt = 0; mt < 4; mt++) {
      int mrow = m0 + wm * 64 + mt * 16 + lg * 4;
      if (Cb) {
#pragma unroll
        for (int r = 0; r < 4; r++)
          Cb[(size_t)(mrow + r) * N + col] = f2bf(acc[mt][nt][r] + bv);
      } else {
#pragma unroll
        for (int r = 0; r < 4; r++)
          C[(size_t)(mrow + r) * N + col] = acc[mt][nt][r] + bv;
      }
    }
  }
}

// ---------------- RoPE for q,k (bf16 in, bf16 out, head-major, pad to 96) ----------------
// q additionally scaled by 80^-0.5 * log2(e) (softmax done in exp2 domain).
__global__ void rope_qk(const short* __restrict__ qkv, const float* __restrict__ cosb,
                        const float* __restrict__ sinb, short* __restrict__ qg,
                        short* __restrict__ kg) {
  int t = blockIdx.x * blockDim.x + threadIdx.x;
  if (t >= SEQ * NHEADS * 40) return;
  int d = t % 40;
  int h = (t / 40) & 15;
  int s = t / 640;
  const short* row = qkv + (size_t)s * (3 * DIM);
  float c0 = cosb[s * HD + d], c1 = cosb[s * HD + d + 40];
  float s0 = sinb[s * HD + d], s1 = sinb[s * HD + d + 40];
  float x1 = bf2f(row[h * HD + d]), x2 = bf2f(row[h * HD + d + 40]);
  float q0 = x1 * c0 - x2 * s0;
  float q1 = x2 * c1 + x1 * s1;
  float y1 = bf2f(row[DIM + h * HD + d]), y2 = bf2f(row[DIM + h * HD + d + 40]);
  float k0 = y1 * c0 - y2 * s0;
  float k1 = y2 * c1 + y1 * s1;
  const float sc = 0.11180339887498949f * 1.4426950408889634f;
  size_t base = ((size_t)h * SEQ + s) * HDP;
  qg[base + d] = f2bf(q0 * sc);
  qg[base + d + 40] = f2bf(q1 * sc);
  kg[base + d] = f2bf(k0);
  kg[base + d + 40] = f2bf(k1);
  if (d < 16) { qg[base + 80 + d] = 0; kg[base + 80 + d] = 0; }
}

// ---------------- V transpose: qkv bf16 (S,3,H,80) -> vt bf16 (H,80,S) ----------------
__global__ void v_transpose(const short* __restrict__ qkv, short* __restrict__ vt) {
  __shared__ short T[16][72];
  int st = blockIdx.x, dt = blockIdx.y, h = blockIdx.z;
  int d0 = dt * 16, s0 = st * 64;
  int t = threadIdx.x;
  int dd = t & 15, ss = t >> 4;
#pragma unroll
  for (int j = 0; j < 4; j++) {
    int s = ss + j * 16;
    T[dd][s] = qkv[(size_t)(s0 + s) * (3 * DIM) + 2 * DIM + h * HD + d0 + dd];
  }
  __syncthreads();
  int s2 = t & 63, dr = t >> 6;
#pragma unroll
  for (int j = 0; j < 4; j++) {
    int d = dr + j * 4;
    vt[((size_t)(h * HD + d0 + d)) * SEQ + s0 + s2] = T[d][s2];
  }
}

// ---------------- flash attention v7 ----------------
// K-LDS coop staging (dbuf, 1 barrier/iter), cvt_pk P-pack, setprio,
// batched V loads after QK. __launch_bounds__(512, 2): hipcc's 2nd arg is
// min BLOCKS/CU — (512,4) capped VGPR at 64 and spilled (r11/r12).
__global__ __launch_bounds__(512, 2) void attn_kernel(
    const short* __restrict__ qg, const short* __restrict__ kg,
    const short* __restrict__ vt, short* __restrict__ out) {
  __shared__ short Ks[2][64 * 128];  // 32 KB (rows padded 96->128 shorts)
  __shared__ short Pl[8][32 * PST];  // 36 KB
  int bid = blockIdx.x;
  int b = bid & 7, h = (bid >> 3) & 15, qt = bid >> 7;
  int tid = threadIdx.x;
  int w = tid >> 6, l = tid & 63;
  int lrow = l & 15, lg = l >> 4;
  int qbase_s = b * SEG + qt * 256 + w * 32;

  const short* qh = qg + (size_t)h * SEQ * HDP;
  const short* kh = kg + (size_t)h * SEQ * HDP;
  const short* vh = vt + (size_t)h * HD * SEQ;

#define STAGE_K(BUF, KEY0N)                                                    \
  {                                                                            \
    _Pragma("unroll") for (int sr = 0; sr < 2; sr++) {                         \
      int sbase = sr * 512 + w * 64;                                           \
      int ss = sbase + l;                                                      \
      int skey = ss >> 4, sc = ss & 15;                                        \
      int slc = sc ^ (skey & 7);                                               \
      const short* ssrc =                                                      \
          kh + (size_t)((KEY0N) + skey) * HDP + (slc < 12 ? slc * 8 : 0);      \
      gload_lds16(ssrc, (char*)&Ks[BUF][0] + sbase * 16);                      \
    }                                                                          \
  }

  bf16x8 qf[2][3];
#pragma unroll
  for (int mt = 0; mt < 2; mt++)
#pragma unroll
    for (int ks = 0; ks < 3; ks++)
      qf[mt][ks] = *(const bf16x8*)&qh[(size_t)(qbase_s + mt * 16 + lrow) * HDP + ks * 32 + lg * 8];

  f32x4 o[2][5] = {};
  float m_st[2] = {-1e30f, -1e30f};
  float l_st[2] = {0.f, 0.f};

  short* Pw = &Pl[w][0];

  STAGE_K(0, b * SEG);
  __syncthreads();

  for (int i = 0; i < NSTEP; i++) {
    int cur = i & 1;
    int key0 = b * SEG + i * KVB;
    if (i + 1 < NSTEP) {
      STAGE_K(cur ^ 1, key0 + KVB);
    }

    // --- QK^T (swapped: mfma(K,Q), col=query, key in-lane) from LDS ---
    f32x4 sv[2][4] = {};
    __builtin_amdgcn_s_setprio(1);
#pragma unroll
    for (int kt = 0; kt < 4; kt++) {
      bf16x8 kf[3];
      int key = kt * 16 + lrow;
#pragma unroll
      for (int ks = 0; ks < 3; ks++) {
        int p = (ks * 4 + lg) ^ (key & 7);
        kf[ks] = *(const bf16x8*)&Ks[cur][key * 128 + p * 8];
      }
#pragma unroll
      for (int mt = 0; mt < 2; mt++)
#pragma unroll
        for (int ks = 0; ks < 3; ks++)
          sv[mt][kt] = __builtin_amdgcn_mfma_f32_16x16x32_bf16(kf[ks], qf[mt][ks], sv[mt][kt], 0, 0, 0);
    }
    __builtin_amdgcn_s_setprio(0);

    // --- V loads, batched here (no fence): latency overlaps softmax below ---
    bf16x8 vf[5][2];
#pragma unroll
    for (int nt = 0; nt < 5; nt++)
#pragma unroll
      for (int ks = 0; ks < 2; ks++)
        vf[nt][ks] = *(const bf16x8*)&vh[(size_t)(nt * 16 + lrow) * SEQ + key0 + ks * 32 + lg * 8];

    // --- per-query tile max: in-lane over 16 keys, then 2 shfl ---
    float cm[2];
#pragma unroll
    for (int mt = 0; mt < 2; mt++) {
      float a0 = fmaxf(fmaxf(sv[mt][0][0], sv[mt][0][1]), fmaxf(sv[mt][0][2], sv[mt][0][3]));
      float a1 = fmaxf(fmaxf(sv[mt][1][0], sv[mt][1][1]), fmaxf(sv[mt][1][2], sv[mt][1][3]));
      float a2 = fmaxf(fmaxf(sv[mt][2][0], sv[mt][2][1]), fmaxf(sv[mt][2][2], sv[mt][2][3]));
      float a3 = fmaxf(fmaxf(sv[mt][3][0], sv[mt][3][1]), fmaxf(sv[mt][3][2], sv[mt][3][3]));
      float c = fmaxf(fmaxf(a0, a1), fmaxf(a2, a3));
      c = fmaxf(c, __shfl_xor(c, 16));
      c = fmaxf(c, __shfl_xor(c, 32));
      cm[mt] = c;
    }
    // defer-max: rescale only when max grew by > 8 (log2 units)
    if (__any((cm[0] > m_st[0] + 8.f) || (cm[1] > m_st[1] + 8.f))) {
#pragma unroll
      for (int mt = 0; mt < 2; mt++) {
        float mn = fmaxf(m_st[mt], cm[mt]);
        float c = fast_exp2(m_st[mt] - mn);
        m_st[mt] = mn;
        l_st[mt] *= c;
        float cr[4];
#pragma unroll
        for (int r = 0; r < 4; r++) cr[r] = __shfl(c, lg * 4 + r);
#pragma unroll
        for (int nt = 0; nt < 5; nt++)
#pragma unroll
          for (int r = 0; r < 4; r++) o[mt][nt][r] *= cr[r];
      }
    }
    // p = exp2(s - m); accumulate l; packed cvt, one b64 LDS write per 4 keys
#pragma unroll
    for (int mt = 0; mt < 2; mt++) {
      float rs = 0.f;
#pragma unroll
      for (int kt = 0; kt < 4; kt++) {
#pragma unroll
        for (int r = 0; r < 4; r++) {
          sv[mt][kt][r] = fast_exp2(sv[mt][kt][r] - m_st[mt]);
          rs += sv[mt][kt][r];
        }
        uint2 pk;
        pk.x = cvt_pk_bf16(sv[mt][kt][0], sv[mt][kt][1]);
        pk.y = cvt_pk_bf16(sv[mt][kt][2], sv[mt][kt][3]);
        *(uint2*)&Pw[(mt * 16 + lrow) * PST + kt * 16 + lg * 4] = pk;
      }
      rs += __shfl_xor(rs, 16);
      rs += __shfl_xor(rs, 32);
      l_st[mt] += rs;
    }

    // --- PV ---
    bf16x8 pa[2][2];
#pragma unroll
    for (int mt = 0; mt < 2; mt++)
#pragma unroll
      for (int ks = 0; ks < 2; ks++)
        pa[mt][ks] = *(const bf16x8*)&Pw[(mt * 16 + lrow) * PST + ks * 32 + lg * 8];
    __builtin_amdgcn_s_setprio(1);
#pragma unroll
    for (int nt = 0; nt < 5; nt++)
#pragma unroll
      for (int mt = 0; mt < 2; mt++)
#pragma unroll
        for (int ks = 0; ks < 2; ks++)
          o[mt][nt] = __builtin_amdgcn_mfma_f32_16x16x32_bf16(pa[mt][ks], vf[nt][ks], o[mt][nt], 0, 0, 0);
    __builtin_amdgcn_s_setprio(0);

    __syncthreads();  // drain K stage; all QK reads of Ks[cur] done
  }

#pragma unroll
  for (int mt = 0; mt < 2; mt++) {
    float rl = 1.f / l_st[mt];
    float ir[4];
#pragma unroll
    for (int r = 0; r < 4; r++) ir[r] = __shfl(rl, lg * 4 + r);
#pragma unroll
    for (int r = 0; r < 4; r++) {
      int srow = qbase_s + mt * 16 + lg * 4 + r;
#pragma unroll
      for (int nt = 0; nt < 5; nt++)
        out[(size_t)srow * DIM + h * HD + nt * 16 + lrow] = f2bf(o[mt][nt][r] * ir[r]);
    }
  }
}

extern "C" void kernel_launch(void* const* d_in, const int* in_sizes, int n_in,
                              void* d_out, int out_size, void* d_ws, size_t ws_size,
                              hipStream_t stream) {
  const float* hidden = (const float*)d_in[0];
  const float* cosb = (const float*)d_in[1];
  const float* sinb = (const float*)d_in[2];
  const float* qkv_w = (const float*)d_in[3];
  const float* qkv_b = (const float*)d_in[4];
  const float* proj_w = (const float*)d_in[5];
  const float* proj_b = (const float*)d_in[6];

  char* ws = (char*)d_ws;
  short* qkv_bf = (short*)(ws);                    // (S,3840) bf16 = 63 MB
  short* attn_o = (short*)(ws);                    // alias (qkv dead by attn)
  short* wp_bf = (short*)(ws + 23068672);          // after attn_o end (21 MB)
  short* q_bf = (short*)(ws + 125829120);
  short* k_bf = (short*)(ws + 150994944);
  short* v_tb = (short*)(ws + 176160768);
  short* h_bf = (short*)(ws + 197132288);
  short* wq_bf = (short*)(ws + 218103808);

  cast_f32_bf16<<<4096, 256, 0, stream>>>(hidden, h_bf, SEQ * DIM);
  cast_f32_bf16<<<4096, 256, 0, stream>>>(qkv_w, wq_bf, 3 * DIM * DIM);
  gemm_bt_bias<<<1920, 256, 0, stream>>>(h_bf, wq_bf, qkv_b, nullptr, qkv_bf, SEQ, 3 * DIM, DIM);
  rope_qk<<<20480, 256, 0, stream>>>(qkv_bf, cosb, sinb, q_bf, k_bf);
  v_transpose<<<dim3(128, 5, 16), 256, 0, stream>>>(qkv_bf, v_tb);
  cast_f32_bf16<<<2048, 256, 0, stream>>>(proj_w, wp_bf, DIM * DIM);
  attn_kernel<<<512, 512, 0, stream>>>(q_bf, k_bf, v_tb, attn_o);
  gemm_bt_bias<<<640, 256, 0, stream>>>(attn_o, wp_bf, proj_b, (float*)d_out, nullptr, SEQ, DIM, DIM);
}